// Round 10
// baseline (553.983 us; speedup 1.0000x reference)
//
#include <hip/hip_runtime.h>

static constexpr float BN_EPS = 1e-5f;
typedef unsigned int uint;
typedef unsigned short ushort;

__device__ __forceinline__ void fatomic_add(float* p, float v) {
  unsafeAtomicAdd(p, v);  // HW global_atomic_add_f32
}

__device__ __forceinline__ ushort f2bf(float f) {  // f32 -> bf16 RNE
  uint u = __float_as_uint(f);
  u += 0x7fffu + ((u >> 16) & 1u);
  return (ushort)(u >> 16);
}

__device__ __forceinline__ float4 bf4_decode(uint2 r) {
  return make_float4(__uint_as_float(r.x << 16), __uint_as_float(r.x & 0xffff0000u),
                     __uint_as_float(r.y << 16), __uint_as_float(r.y & 0xffff0000u));
}

// histogram keyed by col; stores each edge's arrival rank (for atomic-free fill)
__global__ void k_hist(const int* __restrict__ col, int* __restrict__ cnt,
                       int* __restrict__ rank, int e) {
  int i = blockIdx.x * 256 + threadIdx.x;
  if (i < e) rank[i] = atomicAdd(&cnt[col[i]], 1);
}

// ---- device-wide exclusive scan of cnt[n] (1024 elems/block) ----
__global__ __launch_bounds__(256) void k_scan_part(const int* __restrict__ cnt,
                                                   int* __restrict__ bsum, int n) {
  __shared__ int sm[256];
  int t = threadIdx.x;
  int base = blockIdx.x * 1024 + t * 4;
  int s = 0;
#pragma unroll
  for (int j = 0; j < 4; j++) {
    int i = base + j;
    if (i < n) s += cnt[i];
  }
  sm[t] = s;
  __syncthreads();
  for (int off = 128; off > 0; off >>= 1) {
    if (t < off) sm[t] += sm[t + off];
    __syncthreads();
  }
  if (t == 0) bsum[blockIdx.x] = sm[0];
}

__global__ __launch_bounds__(1024) void k_scan_mid(int* __restrict__ bsum, int nb) {
  __shared__ int sm[1024];
  int t = threadIdx.x;
  int v = (t < nb) ? bsum[t] : 0;
  sm[t] = v;
  __syncthreads();
  for (int off = 1; off < 1024; off <<= 1) {
    int o = (t >= off) ? sm[t - off] : 0;
    __syncthreads();
    sm[t] += o;
    __syncthreads();
  }
  if (t < nb) bsum[t] = sm[t] - v;  // exclusive block offsets
}

__global__ __launch_bounds__(256) void k_scan_apply(const int* __restrict__ cnt,
                                                    int* __restrict__ ptr,
                                                    const int* __restrict__ bsum,
                                                    int n, int e) {
  __shared__ int sm[256];
  int t = threadIdx.x;
  int base = blockIdx.x * 1024 + t * 4;
  int v[4];
  int s = 0;
#pragma unroll
  for (int j = 0; j < 4; j++) {
    int i = base + j;
    v[j] = (i < n) ? cnt[i] : 0;
    s += v[j];
  }
  sm[t] = s;
  __syncthreads();
  for (int off = 1; off < 256; off <<= 1) {
    int o = (t >= off) ? sm[t - off] : 0;
    __syncthreads();
    sm[t] += o;
    __syncthreads();
  }
  int run = bsum[blockIdx.x] + sm[t] - s;
#pragma unroll
  for (int j = 0; j < 4; j++) {
    int i = base + j;
    if (i < n) {
      ptr[i] = run;
      run += v[j];
    }
  }
  if (blockIdx.x == 0 && t == 0) ptr[n] = e;
}

// atomic-free CSR fill: slot = ptr[col] + rank
__global__ void k_fillcsr(const int* __restrict__ row, const int* __restrict__ col,
                          const float* __restrict__ ew, const int* __restrict__ ptr,
                          const int* __restrict__ rank, int2* __restrict__ spair, int e) {
  int i = blockIdx.x * 256 + threadIdx.x;
  if (i >= e) return;
  int p = ptr[col[i]] + rank[i];
  spair[p] = make_int2(row[i], __float_as_int(ew[i]));
}

// per-node: deg = 1 (self-loop) + segment-sum of ew; dis = rsqrt(deg). No atomics.
__global__ void k_degdis(const int* __restrict__ ptr, const int2* __restrict__ spair,
                         float* __restrict__ dis, int n) {
  int v = blockIdx.x * 256 + threadIdx.x;
  if (v >= n) return;
  int b = ptr[v], en = ptr[v + 1];
  float s = 1.0f;
  for (int j = b; j < en; j++) s += __int_as_float(spair[j].y);
  dis[v] = rsqrtf(s);
}

// fold dis[row] into stored edge weight (dis[col] applied in k_agg)
__global__ void k_scale(int2* __restrict__ spair, const float* __restrict__ dis, int e) {
  int i = blockIdx.x * 256 + threadIdx.x;
  if (i >= e) return;
  int2 m = spair[i];
  spair[i] = make_int2(m.x, __float_as_int(__int_as_float(m.y) * dis[m.x]));
}

// ---- aggregation v3 + fused BN stats (unchanged).
__global__ __launch_bounds__(256) void k_agg(
    const int* __restrict__ ptr, const int2* __restrict__ spair,
    const float* __restrict__ dis, const ushort* __restrict__ hwb,
    float* __restrict__ agg, float* __restrict__ stats, int n) {
  int lane = threadIdx.x & 63;
  int grp = lane >> 4;
  int li = lane & 15;
  int wid = blockIdx.x * 4 + (threadIdx.x >> 6);
  int nw = gridDim.x * 4;
  float st_s[4] = {0.f, 0.f, 0.f, 0.f};
  float st_q[4] = {0.f, 0.f, 0.f, 0.f};

  for (int vb = wid * 4; vb < n; vb += nw * 4) {
    int v = vb + grp;
    bool on = v < n;
    float4 acc = make_float4(0.f, 0.f, 0.f, 0.f);
    float d = 0.f;
    int beg = 0, end = 0;
    if (on) {
      beg = ptr[v];
      end = ptr[v + 1];
      d = dis[v];
      uint2 rs = *(const uint2*)(hwb + (size_t)v * 64 + li * 4);
      float4 f = bf4_decode(rs);
      acc = make_float4(d * f.x, d * f.y, d * f.z, d * f.w);  // self-loop (1 of 2 dis)
    }
    if (on && beg < end) {
      const int4* sp = (const int4*)spair;
      int jc = beg & ~3;           // 4-edge aligned chunk start
      int h = jc >> 1;             // int4 index of chunk
      int nch = (end - jc + 3) >> 2;
      int4 a0 = sp[h], a1 = sp[h + 1];  // meta chunk 0
      int4 b0, b1;                       // meta chunk c+1 (guarded use)
      if (nch > 1) { b0 = sp[h + 2]; b1 = sp[h + 3]; }
      float wC[4];
      uint2 gC[4];
      {
        int rr[4] = {a0.x, a0.z, a1.x, a1.z};
        int wi[4] = {a0.y, a0.w, a1.y, a1.w};
#pragma unroll
        for (int k = 0; k < 4; k++) {
          int idx = jc + k;
          bool okk = (idx >= beg) && (idx < end);
          int r = okk ? rr[k] : v;
          wC[k] = okk ? __int_as_float(wi[k]) : 0.f;
          gC[k] = *(const uint2*)(hwb + (size_t)r * 64 + li * 4);
        }
      }
      for (int c = 0; c < nch; c++) {
        float wN[4];
        uint2 gN[4];
        if (c + 1 < nch) {  // extract meta(c+1), issue its gathers
          int jn = jc + 4;
          int rr[4] = {b0.x, b0.z, b1.x, b1.z};
          int wi[4] = {b0.y, b0.w, b1.y, b1.w};
#pragma unroll
          for (int k = 0; k < 4; k++) {
            bool okk = (jn + k) < end;
            int r = okk ? rr[k] : v;
            wN[k] = okk ? __int_as_float(wi[k]) : 0.f;
            gN[k] = *(const uint2*)(hwb + (size_t)r * 64 + li * 4);
          }
        }
        if (c + 2 < nch) {  // prefetch meta(c+2)
          b0 = sp[h + 2 * (c + 2)];
          b1 = sp[h + 2 * (c + 2) + 1];
        }
#pragma unroll
        for (int k = 0; k < 4; k++) {  // compute chunk c
          float4 f = bf4_decode(gC[k]);
          acc.x = fmaf(wC[k], f.x, acc.x);
          acc.y = fmaf(wC[k], f.y, acc.y);
          acc.z = fmaf(wC[k], f.z, acc.z);
          acc.w = fmaf(wC[k], f.w, acc.w);
        }
        if (c + 1 < nch) {
#pragma unroll
          for (int k = 0; k < 4; k++) { gC[k] = gN[k]; wC[k] = wN[k]; }
        }
        jc += 4;
      }
    }
    if (on) {
      acc.x *= d; acc.y *= d; acc.z *= d; acc.w *= d;  // 2nd dis factor
      *(float4*)(agg + (size_t)v * 64 + li * 4) = acc;
      st_s[0] += acc.x; st_s[1] += acc.y; st_s[2] += acc.z; st_s[3] += acc.w;
      st_q[0] = fmaf(acc.x, acc.x, st_q[0]);
      st_q[1] = fmaf(acc.y, acc.y, st_q[1]);
      st_q[2] = fmaf(acc.z, acc.z, st_q[2]);
      st_q[3] = fmaf(acc.w, acc.w, st_q[3]);
    }
  }

#pragma unroll
  for (int j = 0; j < 4; j++) {
    st_s[j] += __shfl_xor(st_s[j], 16);
    st_s[j] += __shfl_xor(st_s[j], 32);
    st_q[j] += __shfl_xor(st_q[j], 16);
    st_q[j] += __shfl_xor(st_q[j], 32);
  }
  __shared__ float rs[4][64];
  __shared__ float rq[4][64];
  int wv = threadIdx.x >> 6;
  if (grp == 0) {
#pragma unroll
    for (int j = 0; j < 4; j++) {
      rs[wv][li * 4 + j] = st_s[j];
      rq[wv][li * 4 + j] = st_q[j];
    }
  }
  __syncthreads();
  if (threadIdx.x < 64) {
    int c = threadIdx.x;
    float s = rs[0][c] + rs[1][c] + rs[2][c] + rs[3][c];
    float q = rq[0][c] + rq[1][c] + rq[2][c] + rq[3][c];
    fatomic_add(&stats[c], s);
    fatomic_add(&stats[64 + c], q);
  }
}

// ---- GEMM1 (specialized): [n,128] @ [128,128], cols 0-63 -> bf16 hw (W1),
// cols 64-127 -> f32 residual (pW + pb). 8-col segments: CS=16, RS=16, ROWS=8
// -> TR=128 (782 blocks, no grid tail). Per u-step each thread does 2 LDS
// float4 reads for 64 FMAs -> VALU-bound. LDS slot (c4&1)*16+(c4>>1): reads
// for fixed q are 16 consecutive float4 (2-way aliasing = free); writes
// spread uniformly (minimal bank rounds).
__global__ __launch_bounds__(256) void k_gemm1(
    const float* __restrict__ x, const float* __restrict__ Wa,
    const float* __restrict__ Wb, const float* __restrict__ bb,
    ushort* __restrict__ ob, float* __restrict__ of, int n) {
  constexpr int KT = 64;
  __shared__ float wS[KT * 128];
  int tid = threadIdx.x;
  int cseg = tid & 15;
  int rslot = tid >> 4;
  int baseRow = blockIdx.x * 128;

  float acc[8][8];
#pragma unroll
  for (int i = 0; i < 8; i++)
#pragma unroll
    for (int j = 0; j < 8; j++) acc[i][j] = 0.f;

  int rows[8];
  bool ok[8];
#pragma unroll
  for (int i = 0; i < 8; i++) {
    rows[i] = baseRow + rslot + i * 16;
    ok[i] = rows[i] < n;
  }

  for (int kt = 0; kt < 128; kt += KT) {
    __syncthreads();
    for (int idx = tid; idx < KT * 32; idx += 256) {
      int kk = idx >> 5;
      int c4 = idx & 31;
      const float* src = (c4 >= 16) ? Wb : Wa;
      int cc = c4 & 15;
      int slot = (c4 & 1) * 16 + (c4 >> 1);
      ((float4*)wS)[(kk << 5) + slot] = ((const float4*)(src + (size_t)(kt + kk) * 64))[cc];
    }
    __syncthreads();
#pragma unroll 2
    for (int k4 = 0; k4 < KT / 4; k4++) {
      float4 xv[8];
#pragma unroll
      for (int i = 0; i < 8; i++)
        xv[i] = ok[i] ? *(const float4*)(x + (size_t)rows[i] * 128 + kt + k4 * 4)
                      : make_float4(0.f, 0.f, 0.f, 0.f);
#pragma unroll
      for (int u = 0; u < 4; u++) {
        const float4* wrow = ((const float4*)wS) + (k4 * 4 + u) * 32;
        float4 w0 = wrow[cseg];
        float4 w1 = wrow[16 + cseg];
#pragma unroll
        for (int i = 0; i < 8; i++) {
          float ak = (u == 0) ? xv[i].x : (u == 1) ? xv[i].y : (u == 2) ? xv[i].z : xv[i].w;
          acc[i][0] = fmaf(ak, w0.x, acc[i][0]);
          acc[i][1] = fmaf(ak, w0.y, acc[i][1]);
          acc[i][2] = fmaf(ak, w0.z, acc[i][2]);
          acc[i][3] = fmaf(ak, w0.w, acc[i][3]);
          acc[i][4] = fmaf(ak, w1.x, acc[i][4]);
          acc[i][5] = fmaf(ak, w1.y, acc[i][5]);
          acc[i][6] = fmaf(ak, w1.z, acc[i][6]);
          acc[i][7] = fmaf(ak, w1.w, acc[i][7]);
        }
      }
    }
  }

  if (cseg < 8) {  // bf16 half: cols cseg*8 .. cseg*8+7
    int co = cseg * 8;
#pragma unroll
    for (int i = 0; i < 8; i++) {
      if (!ok[i]) continue;
      ushort* o = ob + (size_t)rows[i] * 64 + co;
      uint pk[4];
#pragma unroll
      for (int q = 0; q < 4; q++)
        pk[q] = (uint)f2bf(acc[i][2 * q]) | ((uint)f2bf(acc[i][2 * q + 1]) << 16);
      *((uint4*)o) = make_uint4(pk[0], pk[1], pk[2], pk[3]);
    }
  } else {  // f32 residual half with bias
    int cs = cseg - 8;
    int co = cs * 8;
    float4 b0 = ((const float4*)bb)[cs * 2];
    float4 b1 = ((const float4*)bb)[cs * 2 + 1];
#pragma unroll
    for (int i = 0; i < 8; i++) {
      if (!ok[i]) continue;
      float* o = of + (size_t)rows[i] * 64 + co;
      ((float4*)o)[0] = make_float4(acc[i][0] + b0.x, acc[i][1] + b0.y,
                                    acc[i][2] + b0.z, acc[i][3] + b0.w);
      ((float4*)o)[1] = make_float4(acc[i][4] + b1.x, acc[i][5] + b1.y,
                                    acc[i][6] + b1.z, acc[i][7] + b1.w);
    }
  }
}

// ---- GEMM2 (generic template, as R9): [n,K] @ [K,N], ROWS x 16-col per thread.
template <int K, int N, int KT, int ROWS, bool SPLIT>
__global__ __launch_bounds__(256) void k_gemmv(
    const float* __restrict__ x, const float* __restrict__ Wa,
    const float* __restrict__ Wb, const float* __restrict__ bb,
    ushort* __restrict__ ob, float* __restrict__ of, int n) {
  constexpr int CS = N / 16;
  constexpr int RS = 256 / CS;
  constexpr int TR = RS * ROWS;
  __shared__ float wS[KT * N];
  int tid = threadIdx.x;
  int cseg = tid % CS;
  int rslot = tid / CS;
  int baseRow = blockIdx.x * TR;

  float acc[ROWS][16];
#pragma unroll
  for (int i = 0; i < ROWS; i++)
#pragma unroll
    for (int j = 0; j < 16; j++) acc[i][j] = 0.f;

  int rows[ROWS];
  bool ok[ROWS];
#pragma unroll
  for (int i = 0; i < ROWS; i++) {
    rows[i] = baseRow + rslot + i * RS;
    ok[i] = rows[i] < n;
  }

  for (int kt = 0; kt < K; kt += KT) {
    __syncthreads();
    for (int idx = tid; idx < KT * N / 4; idx += 256) {
      int kk = idx / (N / 4);
      int c4 = idx % (N / 4);
      const float* src = (SPLIT && c4 >= 16) ? Wb : Wa;
      int cc = SPLIT ? (c4 & 15) : c4;
      int slot = (c4 & 3) * CS + (c4 >> 2);
      ((float4*)wS)[kk * (N / 4) + slot] = ((const float4*)(src + (size_t)(kt + kk) * 64))[cc];
    }
    __syncthreads();
#pragma unroll 2
    for (int k4 = 0; k4 < KT / 4; k4++) {
      float4 xv[ROWS];
#pragma unroll
      for (int i = 0; i < ROWS; i++)
        xv[i] = ok[i] ? *(const float4*)(x + (size_t)rows[i] * K + kt + k4 * 4)
                      : make_float4(0.f, 0.f, 0.f, 0.f);
#pragma unroll
      for (int u = 0; u < 4; u++) {
        const float4* wrow = ((const float4*)wS) + (k4 * 4 + u) * (N / 4);
        float4 w0 = wrow[0 * CS + cseg];
        float4 w1 = wrow[1 * CS + cseg];
        float4 w2 = wrow[2 * CS + cseg];
        float4 w3 = wrow[3 * CS + cseg];
#pragma unroll
        for (int i = 0; i < ROWS; i++) {
          float ak = (u == 0) ? xv[i].x : (u == 1) ? xv[i].y : (u == 2) ? xv[i].z : xv[i].w;
          acc[i][0] = fmaf(ak, w0.x, acc[i][0]);
          acc[i][1] = fmaf(ak, w0.y, acc[i][1]);
          acc[i][2] = fmaf(ak, w0.z, acc[i][2]);
          acc[i][3] = fmaf(ak, w0.w, acc[i][3]);
          acc[i][4] = fmaf(ak, w1.x, acc[i][4]);
          acc[i][5] = fmaf(ak, w1.y, acc[i][5]);
          acc[i][6] = fmaf(ak, w1.z, acc[i][6]);
          acc[i][7] = fmaf(ak, w1.w, acc[i][7]);
          acc[i][8] = fmaf(ak, w2.x, acc[i][8]);
          acc[i][9] = fmaf(ak, w2.y, acc[i][9]);
          acc[i][10] = fmaf(ak, w2.z, acc[i][10]);
          acc[i][11] = fmaf(ak, w2.w, acc[i][11]);
          acc[i][12] = fmaf(ak, w3.x, acc[i][12]);
          acc[i][13] = fmaf(ak, w3.y, acc[i][13]);
          acc[i][14] = fmaf(ak, w3.z, acc[i][14]);
          acc[i][15] = fmaf(ak, w3.w, acc[i][15]);
        }
      }
    }
  }

  if (!SPLIT || cseg < CS / 2) {
    int co = cseg * 16;
#pragma unroll
    for (int i = 0; i < ROWS; i++) {
      if (!ok[i]) continue;
      ushort* o = ob + (size_t)rows[i] * 64 + co;
      uint pk[8];
#pragma unroll
      for (int q = 0; q < 8; q++)
        pk[q] = (uint)f2bf(acc[i][2 * q]) | ((uint)f2bf(acc[i][2 * q + 1]) << 16);
      ((uint4*)o)[0] = make_uint4(pk[0], pk[1], pk[2], pk[3]);
      ((uint4*)o)[1] = make_uint4(pk[4], pk[5], pk[6], pk[7]);
    }
  } else {
    int cs = cseg - CS / 2;
    float4 bv[4];
#pragma unroll
    for (int q = 0; q < 4; q++) bv[q] = ((const float4*)bb)[cs * 4 + q];
#pragma unroll
    for (int i = 0; i < ROWS; i++) {
      if (!ok[i]) continue;
      float* o = of + (size_t)rows[i] * 64 + cs * 16;
#pragma unroll
      for (int q = 0; q < 4; q++)
        ((float4*)o)[q] = make_float4(acc[i][q * 4 + 0] + bv[q].x, acc[i][q * 4 + 1] + bv[q].y,
                                      acc[i][q * 4 + 2] + bv[q].z, acc[i][q * 4 + 3] + bv[q].w);
    }
  }
}

// out = relu(g*(agg-mu)*rsqrt(var+eps)+beta) + res   (conv bias cancels in BN)
__global__ __launch_bounds__(256) void k_bnrelu(
    const float* __restrict__ agg, const float* __restrict__ res,
    const float* __restrict__ stats, const float* __restrict__ g,
    const float* __restrict__ beta, float* __restrict__ out, int n) {
  int idx = blockIdx.x * 256 + threadIdx.x;
  if (idx >= n * 16) return;
  int c4 = (idx & 15) * 4;
  float invN = 1.0f / (float)n;
  float4 a = ((const float4*)agg)[idx];
  float4 rr = ((const float4*)res)[idx];
  float av[4] = {a.x, a.y, a.z, a.w};
  float rv[4] = {rr.x, rr.y, rr.z, rr.w};
  float vo[4];
#pragma unroll
  for (int j = 0; j < 4; j++) {
    int c = c4 + j;
    float mu = stats[c] * invN;
    float var = stats[64 + c] * invN - mu * mu;
    float sc = g[c] * rsqrtf(var + BN_EPS);
    float v = (av[j] - mu) * sc + beta[c];
    vo[j] = fmaxf(v, 0.0f) + rv[j];
  }
  ((float4*)out)[idx] = make_float4(vo[0], vo[1], vo[2], vo[3]);
}

extern "C" void kernel_launch(void* const* d_in, const int* in_sizes, int n_in,
                              void* d_out, int out_size, void* d_ws, size_t ws_size,
                              hipStream_t stream) {
  const float* x = (const float*)d_in[0];
  const int* ei = (const int*)d_in[1];
  const float* ew = (const float*)d_in[2];
  const float* W1 = (const float*)d_in[3];
  const float* g1 = (const float*)d_in[5];
  const float* be1 = (const float*)d_in[6];
  const float* W2 = (const float*)d_in[7];
  const float* g2 = (const float*)d_in[9];
  const float* be2 = (const float*)d_in[10];
  const float* pW = (const float*)d_in[11];
  const float* pb = (const float*)d_in[12];

  int n = in_sizes[0] / 128;
  int e = in_sizes[1] / 2;
  const int* row = ei;      // source
  const int* col = ei + e;  // target

  // workspace layout (spair padded by 16 int2: chunked k_agg may over-READ
  // up to 3 entries past e; masked before use)
  float* ws = (float*)d_ws;
  float* dis = ws;                             // n
  int* ptr = (int*)(dis + n);                  // n+4
  int* cnt = ptr + n + 4;                      // n
  int* rank = cnt + n;                         // e
  int* bsum = rank + e;                        // 1024
  int2* spair = (int2*)(bsum + 1024);          // e int2 (+16 pad)
  ushort* hwb = (ushort*)(spair + e + 16);     // n*64 bf16 (hw1, then hw2)
  float* bufR = (float*)(hwb + (size_t)n * 64);  // n*64 (residual)
  float* bufB = bufR + (size_t)n * 64;         // n*64 (agg)
  float* bufA = bufB + (size_t)n * 64;         // n*64 (h)
  float* stats = bufA + (size_t)n * 64;        // 128

  float* out = (float*)d_out;

  int nb_n = (n + 255) / 256;
  int nb_e = (e + 255) / 256;
  int nb_b = (n * 16 + 255) / 256;
  int nb_sc = (n + 1023) / 1024;
  int nb_g1 = (n + 127) / 128;  // TR=128 (k_gemm1)
  int nb_g2 = (n + 255) / 256;  // TR=256 (ROWS=4, N=64)

  // CSR build + gcn_norm
  hipMemsetAsync(cnt, 0, n * sizeof(int), stream);
  k_hist<<<nb_e, 256, 0, stream>>>(col, cnt, rank, e);
  k_scan_part<<<nb_sc, 256, 0, stream>>>(cnt, bsum, n);
  k_scan_mid<<<1, 1024, 0, stream>>>(bsum, nb_sc);
  k_scan_apply<<<nb_sc, 256, 0, stream>>>(cnt, ptr, bsum, n, e);
  k_fillcsr<<<nb_e, 256, 0, stream>>>(row, col, ew, ptr, rank, spair, e);
  k_degdis<<<nb_n, 256, 0, stream>>>(ptr, spair, dis, n);
  k_scale<<<nb_e, 256, 0, stream>>>(spair, dis, e);

  // layer 1: combined [x@W1 -> bf16 hwb | x@pW + pb -> f32 bufR]
  k_gemm1<<<nb_g1, 256, 0, stream>>>(x, W1, pW, pb, hwb, bufR, n);
  hipMemsetAsync(stats, 0, 128 * sizeof(float), stream);
  k_agg<<<2048, 256, 0, stream>>>(ptr, spair, dis, hwb, bufB, stats, n);
  k_bnrelu<<<nb_b, 256, 0, stream>>>(bufB, bufR, stats, g1, be1, bufA, n);

  // layer 2
  k_gemmv<64, 64, 64, 4, false><<<nb_g2, 256, 0, stream>>>(bufA, W2, nullptr, nullptr, hwb, nullptr, n);
  hipMemsetAsync(stats, 0, 128 * sizeof(float), stream);
  k_agg<<<2048, 256, 0, stream>>>(ptr, spair, dis, hwb, bufB, stats, n);
  k_bnrelu<<<nb_b, 256, 0, stream>>>(bufB, bufA, stats, g2, be2, out, n);
}

// Round 11
// 472.034 us; speedup vs baseline: 1.1736x; 1.1736x over previous
//
#include <hip/hip_runtime.h>

static constexpr float BN_EPS = 1e-5f;
typedef unsigned int uint;
typedef unsigned short ushort;

__device__ __forceinline__ void fatomic_add(float* p, float v) {
  unsafeAtomicAdd(p, v);  // HW global_atomic_add_f32
}

__device__ __forceinline__ ushort f2bf(float f) {  // f32 -> bf16 RNE
  uint u = __float_as_uint(f);
  u += 0x7fffu + ((u >> 16) & 1u);
  return (ushort)(u >> 16);
}

__device__ __forceinline__ float4 bf4_decode(uint2 r) {
  return make_float4(__uint_as_float(r.x << 16), __uint_as_float(r.x & 0xffff0000u),
                     __uint_as_float(r.y << 16), __uint_as_float(r.y & 0xffff0000u));
}

// histogram keyed by col; stores each edge's arrival rank (for atomic-free fill)
__global__ void k_hist(const int* __restrict__ col, int* __restrict__ cnt,
                       int* __restrict__ rank, int e) {
  int i = blockIdx.x * 256 + threadIdx.x;
  if (i < e) rank[i] = atomicAdd(&cnt[col[i]], 1);
}

// ---- device-wide exclusive scan of cnt[n] (1024 elems/block) ----
__global__ __launch_bounds__(256) void k_scan_part(const int* __restrict__ cnt,
                                                   int* __restrict__ bsum, int n) {
  __shared__ int sm[256];
  int t = threadIdx.x;
  int base = blockIdx.x * 1024 + t * 4;
  int s = 0;
#pragma unroll
  for (int j = 0; j < 4; j++) {
    int i = base + j;
    if (i < n) s += cnt[i];
  }
  sm[t] = s;
  __syncthreads();
  for (int off = 128; off > 0; off >>= 1) {
    if (t < off) sm[t] += sm[t + off];
    __syncthreads();
  }
  if (t == 0) bsum[blockIdx.x] = sm[0];
}

__global__ __launch_bounds__(1024) void k_scan_mid(int* __restrict__ bsum, int nb) {
  __shared__ int sm[1024];
  int t = threadIdx.x;
  int v = (t < nb) ? bsum[t] : 0;
  sm[t] = v;
  __syncthreads();
  for (int off = 1; off < 1024; off <<= 1) {
    int o = (t >= off) ? sm[t - off] : 0;
    __syncthreads();
    sm[t] += o;
    __syncthreads();
  }
  if (t < nb) bsum[t] = sm[t] - v;  // exclusive block offsets
}

__global__ __launch_bounds__(256) void k_scan_apply(const int* __restrict__ cnt,
                                                    int* __restrict__ ptr,
                                                    const int* __restrict__ bsum,
                                                    int n, int e) {
  __shared__ int sm[256];
  int t = threadIdx.x;
  int base = blockIdx.x * 1024 + t * 4;
  int v[4];
  int s = 0;
#pragma unroll
  for (int j = 0; j < 4; j++) {
    int i = base + j;
    v[j] = (i < n) ? cnt[i] : 0;
    s += v[j];
  }
  sm[t] = s;
  __syncthreads();
  for (int off = 1; off < 256; off <<= 1) {
    int o = (t >= off) ? sm[t - off] : 0;
    __syncthreads();
    sm[t] += o;
    __syncthreads();
  }
  int run = bsum[blockIdx.x] + sm[t] - s;
#pragma unroll
  for (int j = 0; j < 4; j++) {
    int i = base + j;
    if (i < n) {
      ptr[i] = run;
      run += v[j];
    }
  }
  if (blockIdx.x == 0 && t == 0) ptr[n] = e;
}

// atomic-free CSR fill: slot = ptr[col] + rank
__global__ void k_fillcsr(const int* __restrict__ row, const int* __restrict__ col,
                          const float* __restrict__ ew, const int* __restrict__ ptr,
                          const int* __restrict__ rank, int2* __restrict__ spair, int e) {
  int i = blockIdx.x * 256 + threadIdx.x;
  if (i >= e) return;
  int p = ptr[col[i]] + rank[i];
  spair[p] = make_int2(row[i], __float_as_int(ew[i]));
}

// per-node: deg = 1 (self-loop) + segment-sum of ew; dis = rsqrt(deg). No atomics.
__global__ void k_degdis(const int* __restrict__ ptr, const int2* __restrict__ spair,
                         float* __restrict__ dis, int n) {
  int v = blockIdx.x * 256 + threadIdx.x;
  if (v >= n) return;
  int b = ptr[v], en = ptr[v + 1];
  float s = 1.0f;
  for (int j = b; j < en; j++) s += __int_as_float(spair[j].y);
  dis[v] = rsqrtf(s);
}

// fold dis[row] into stored edge weight (dis[col] applied in k_agg)
__global__ void k_scale(int2* __restrict__ spair, const float* __restrict__ dis, int e) {
  int i = blockIdx.x * 256 + threadIdx.x;
  if (i >= e) return;
  int2 m = spair[i];
  spair[i] = make_int2(m.x, __float_as_int(__int_as_float(m.y) * dis[m.x]));
}

// ---- aggregation v3 + fused BN stats (unchanged).
__global__ __launch_bounds__(256) void k_agg(
    const int* __restrict__ ptr, const int2* __restrict__ spair,
    const float* __restrict__ dis, const ushort* __restrict__ hwb,
    float* __restrict__ agg, float* __restrict__ stats, int n) {
  int lane = threadIdx.x & 63;
  int grp = lane >> 4;
  int li = lane & 15;
  int wid = blockIdx.x * 4 + (threadIdx.x >> 6);
  int nw = gridDim.x * 4;
  float st_s[4] = {0.f, 0.f, 0.f, 0.f};
  float st_q[4] = {0.f, 0.f, 0.f, 0.f};

  for (int vb = wid * 4; vb < n; vb += nw * 4) {
    int v = vb + grp;
    bool on = v < n;
    float4 acc = make_float4(0.f, 0.f, 0.f, 0.f);
    float d = 0.f;
    int beg = 0, end = 0;
    if (on) {
      beg = ptr[v];
      end = ptr[v + 1];
      d = dis[v];
      uint2 rs = *(const uint2*)(hwb + (size_t)v * 64 + li * 4);
      float4 f = bf4_decode(rs);
      acc = make_float4(d * f.x, d * f.y, d * f.z, d * f.w);  // self-loop (1 of 2 dis)
    }
    if (on && beg < end) {
      const int4* sp = (const int4*)spair;
      int jc = beg & ~3;           // 4-edge aligned chunk start
      int h = jc >> 1;             // int4 index of chunk
      int nch = (end - jc + 3) >> 2;
      int4 a0 = sp[h], a1 = sp[h + 1];  // meta chunk 0
      int4 b0, b1;                       // meta chunk c+1 (guarded use)
      if (nch > 1) { b0 = sp[h + 2]; b1 = sp[h + 3]; }
      float wC[4];
      uint2 gC[4];
      {
        int rr[4] = {a0.x, a0.z, a1.x, a1.z};
        int wi[4] = {a0.y, a0.w, a1.y, a1.w};
#pragma unroll
        for (int k = 0; k < 4; k++) {
          int idx = jc + k;
          bool okk = (idx >= beg) && (idx < end);
          int r = okk ? rr[k] : v;
          wC[k] = okk ? __int_as_float(wi[k]) : 0.f;
          gC[k] = *(const uint2*)(hwb + (size_t)r * 64 + li * 4);
        }
      }
      for (int c = 0; c < nch; c++) {
        float wN[4];
        uint2 gN[4];
        if (c + 1 < nch) {  // extract meta(c+1), issue its gathers
          int jn = jc + 4;
          int rr[4] = {b0.x, b0.z, b1.x, b1.z};
          int wi[4] = {b0.y, b0.w, b1.y, b1.w};
#pragma unroll
          for (int k = 0; k < 4; k++) {
            bool okk = (jn + k) < end;
            int r = okk ? rr[k] : v;
            wN[k] = okk ? __int_as_float(wi[k]) : 0.f;
            gN[k] = *(const uint2*)(hwb + (size_t)r * 64 + li * 4);
          }
        }
        if (c + 2 < nch) {  // prefetch meta(c+2)
          b0 = sp[h + 2 * (c + 2)];
          b1 = sp[h + 2 * (c + 2) + 1];
        }
#pragma unroll
        for (int k = 0; k < 4; k++) {  // compute chunk c
          float4 f = bf4_decode(gC[k]);
          acc.x = fmaf(wC[k], f.x, acc.x);
          acc.y = fmaf(wC[k], f.y, acc.y);
          acc.z = fmaf(wC[k], f.z, acc.z);
          acc.w = fmaf(wC[k], f.w, acc.w);
        }
        if (c + 1 < nch) {
#pragma unroll
          for (int k = 0; k < 4; k++) { gC[k] = gN[k]; wC[k] = wN[k]; }
        }
        jc += 4;
      }
    }
    if (on) {
      acc.x *= d; acc.y *= d; acc.z *= d; acc.w *= d;  // 2nd dis factor
      *(float4*)(agg + (size_t)v * 64 + li * 4) = acc;
      st_s[0] += acc.x; st_s[1] += acc.y; st_s[2] += acc.z; st_s[3] += acc.w;
      st_q[0] = fmaf(acc.x, acc.x, st_q[0]);
      st_q[1] = fmaf(acc.y, acc.y, st_q[1]);
      st_q[2] = fmaf(acc.z, acc.z, st_q[2]);
      st_q[3] = fmaf(acc.w, acc.w, st_q[3]);
    }
  }

#pragma unroll
  for (int j = 0; j < 4; j++) {
    st_s[j] += __shfl_xor(st_s[j], 16);
    st_s[j] += __shfl_xor(st_s[j], 32);
    st_q[j] += __shfl_xor(st_q[j], 16);
    st_q[j] += __shfl_xor(st_q[j], 32);
  }
  __shared__ float rs[4][64];
  __shared__ float rq[4][64];
  int wv = threadIdx.x >> 6;
  if (grp == 0) {
#pragma unroll
    for (int j = 0; j < 4; j++) {
      rs[wv][li * 4 + j] = st_s[j];
      rq[wv][li * 4 + j] = st_q[j];
    }
  }
  __syncthreads();
  if (threadIdx.x < 64) {
    int c = threadIdx.x;
    float s = rs[0][c] + rs[1][c] + rs[2][c] + rs[3][c];
    float q = rq[0][c] + rq[1][c] + rq[2][c] + rq[3][c];
    fatomic_add(&stats[c], s);
    fatomic_add(&stats[64 + c], q);
  }
}

// ---- GEMM: [n,K] @ [K,N], ROWS rows x 16 cols per thread.
// R7 structure (ROWS=4, TR=128 for GEMM1: VGPR~112, 4 waves/SIMD) + LDS slot
// permutation: float4 (k,c4) stored at slot (c4&3)*CS + (c4>>2). Reads for
// fixed q across the CS csegs cover CS consecutive float4s (banks used exactly
// once -> conflict-free); staging writes are bijective (minimal bank rounds).
template <int K, int N, int KT, int ROWS, bool SPLIT>
__global__ __launch_bounds__(256) void k_gemmv(
    const float* __restrict__ x, const float* __restrict__ Wa,
    const float* __restrict__ Wb, const float* __restrict__ bb,
    ushort* __restrict__ ob, float* __restrict__ of, int n) {
  constexpr int CS = N / 16;
  constexpr int RS = 256 / CS;
  constexpr int TR = RS * ROWS;
  __shared__ float wS[KT * N];
  int tid = threadIdx.x;
  int cseg = tid % CS;
  int rslot = tid / CS;
  int baseRow = blockIdx.x * TR;

  float acc[ROWS][16];
#pragma unroll
  for (int i = 0; i < ROWS; i++)
#pragma unroll
    for (int j = 0; j < 16; j++) acc[i][j] = 0.f;

  int rows[ROWS];
  bool ok[ROWS];
#pragma unroll
  for (int i = 0; i < ROWS; i++) {
    rows[i] = baseRow + rslot + i * RS;
    ok[i] = rows[i] < n;
  }

  for (int kt = 0; kt < K; kt += KT) {
    __syncthreads();
    for (int idx = tid; idx < KT * N / 4; idx += 256) {
      int kk = idx / (N / 4);
      int c4 = idx % (N / 4);
      const float* src = (SPLIT && c4 >= 16) ? Wb : Wa;
      int cc = SPLIT ? (c4 & 15) : c4;
      int slot = (c4 & 3) * CS + (c4 >> 2);  // conflict-free permutation
      ((float4*)wS)[kk * (N / 4) + slot] = ((const float4*)(src + (size_t)(kt + kk) * 64))[cc];
    }
    __syncthreads();
#pragma unroll 2
    for (int k4 = 0; k4 < KT / 4; k4++) {
      float4 xv[ROWS];
#pragma unroll
      for (int i = 0; i < ROWS; i++)
        xv[i] = ok[i] ? *(const float4*)(x + (size_t)rows[i] * K + kt + k4 * 4)
                      : make_float4(0.f, 0.f, 0.f, 0.f);
#pragma unroll
      for (int u = 0; u < 4; u++) {
        const float4* wrow = ((const float4*)wS) + (k4 * 4 + u) * (N / 4);
        float4 w0 = wrow[0 * CS + cseg];
        float4 w1 = wrow[1 * CS + cseg];
        float4 w2 = wrow[2 * CS + cseg];
        float4 w3 = wrow[3 * CS + cseg];
#pragma unroll
        for (int i = 0; i < ROWS; i++) {
          float ak = (u == 0) ? xv[i].x : (u == 1) ? xv[i].y : (u == 2) ? xv[i].z : xv[i].w;
          acc[i][0] = fmaf(ak, w0.x, acc[i][0]);
          acc[i][1] = fmaf(ak, w0.y, acc[i][1]);
          acc[i][2] = fmaf(ak, w0.z, acc[i][2]);
          acc[i][3] = fmaf(ak, w0.w, acc[i][3]);
          acc[i][4] = fmaf(ak, w1.x, acc[i][4]);
          acc[i][5] = fmaf(ak, w1.y, acc[i][5]);
          acc[i][6] = fmaf(ak, w1.z, acc[i][6]);
          acc[i][7] = fmaf(ak, w1.w, acc[i][7]);
          acc[i][8] = fmaf(ak, w2.x, acc[i][8]);
          acc[i][9] = fmaf(ak, w2.y, acc[i][9]);
          acc[i][10] = fmaf(ak, w2.z, acc[i][10]);
          acc[i][11] = fmaf(ak, w2.w, acc[i][11]);
          acc[i][12] = fmaf(ak, w3.x, acc[i][12]);
          acc[i][13] = fmaf(ak, w3.y, acc[i][13]);
          acc[i][14] = fmaf(ak, w3.z, acc[i][14]);
          acc[i][15] = fmaf(ak, w3.w, acc[i][15]);
        }
      }
    }
  }

  if (!SPLIT || cseg < CS / 2) {  // bf16 output half (or all, for N=64)
    int co = cseg * 16;
#pragma unroll
    for (int i = 0; i < ROWS; i++) {
      if (!ok[i]) continue;
      ushort* o = ob + (size_t)rows[i] * 64 + co;
      uint pk[8];
#pragma unroll
      for (int q = 0; q < 8; q++)
        pk[q] = (uint)f2bf(acc[i][2 * q]) | ((uint)f2bf(acc[i][2 * q + 1]) << 16);
      ((uint4*)o)[0] = make_uint4(pk[0], pk[1], pk[2], pk[3]);
      ((uint4*)o)[1] = make_uint4(pk[4], pk[5], pk[6], pk[7]);
    }
  } else {  // f32 residual half with bias
    int cs = cseg - CS / 2;
    float4 bv[4];
#pragma unroll
    for (int q = 0; q < 4; q++) bv[q] = ((const float4*)bb)[cs * 4 + q];
#pragma unroll
    for (int i = 0; i < ROWS; i++) {
      if (!ok[i]) continue;
      float* o = of + (size_t)rows[i] * 64 + cs * 16;
#pragma unroll
      for (int q = 0; q < 4; q++)
        ((float4*)o)[q] = make_float4(acc[i][q * 4 + 0] + bv[q].x, acc[i][q * 4 + 1] + bv[q].y,
                                      acc[i][q * 4 + 2] + bv[q].z, acc[i][q * 4 + 3] + bv[q].w);
    }
  }
}

// out = relu(g*(agg-mu)*rsqrt(var+eps)+beta) + res   (conv bias cancels in BN)
__global__ __launch_bounds__(256) void k_bnrelu(
    const float* __restrict__ agg, const float* __restrict__ res,
    const float* __restrict__ stats, const float* __restrict__ g,
    const float* __restrict__ beta, float* __restrict__ out, int n) {
  int idx = blockIdx.x * 256 + threadIdx.x;
  if (idx >= n * 16) return;
  int c4 = (idx & 15) * 4;
  float invN = 1.0f / (float)n;
  float4 a = ((const float4*)agg)[idx];
  float4 rr = ((const float4*)res)[idx];
  float av[4] = {a.x, a.y, a.z, a.w};
  float rv[4] = {rr.x, rr.y, rr.z, rr.w};
  float vo[4];
#pragma unroll
  for (int j = 0; j < 4; j++) {
    int c = c4 + j;
    float mu = stats[c] * invN;
    float var = stats[64 + c] * invN - mu * mu;
    float sc = g[c] * rsqrtf(var + BN_EPS);
    float v = (av[j] - mu) * sc + beta[c];
    vo[j] = fmaxf(v, 0.0f) + rv[j];
  }
  ((float4*)out)[idx] = make_float4(vo[0], vo[1], vo[2], vo[3]);
}

extern "C" void kernel_launch(void* const* d_in, const int* in_sizes, int n_in,
                              void* d_out, int out_size, void* d_ws, size_t ws_size,
                              hipStream_t stream) {
  const float* x = (const float*)d_in[0];
  const int* ei = (const int*)d_in[1];
  const float* ew = (const float*)d_in[2];
  const float* W1 = (const float*)d_in[3];
  const float* g1 = (const float*)d_in[5];
  const float* be1 = (const float*)d_in[6];
  const float* W2 = (const float*)d_in[7];
  const float* g2 = (const float*)d_in[9];
  const float* be2 = (const float*)d_in[10];
  const float* pW = (const float*)d_in[11];
  const float* pb = (const float*)d_in[12];

  int n = in_sizes[0] / 128;
  int e = in_sizes[1] / 2;
  const int* row = ei;      // source
  const int* col = ei + e;  // target

  // workspace layout (spair padded by 16 int2: chunked k_agg may over-READ
  // up to 3 entries past e; masked before use)
  float* ws = (float*)d_ws;
  float* dis = ws;                             // n
  int* ptr = (int*)(dis + n);                  // n+4
  int* cnt = ptr + n + 4;                      // n
  int* rank = cnt + n;                         // e
  int* bsum = rank + e;                        // 1024
  int2* spair = (int2*)(bsum + 1024);          // e int2 (+16 pad)
  ushort* hwb = (ushort*)(spair + e + 16);     // n*64 bf16 (hw1, then hw2)
  float* bufR = (float*)(hwb + (size_t)n * 64);  // n*64 (residual)
  float* bufB = bufR + (size_t)n * 64;         // n*64 (agg)
  float* bufA = bufB + (size_t)n * 64;         // n*64 (h)
  float* stats = bufA + (size_t)n * 64;        // 128

  float* out = (float*)d_out;

  int nb_n = (n + 255) / 256;
  int nb_e = (e + 255) / 256;
  int nb_b = (n * 16 + 255) / 256;
  int nb_sc = (n + 1023) / 1024;
  int nb_g1 = (n + 127) / 128;  // TR=128 (ROWS=4, N=128)
  int nb_g2 = (n + 255) / 256;  // TR=256 (ROWS=4, N=64)

  // CSR build + gcn_norm
  hipMemsetAsync(cnt, 0, n * sizeof(int), stream);
  k_hist<<<nb_e, 256, 0, stream>>>(col, cnt, rank, e);
  k_scan_part<<<nb_sc, 256, 0, stream>>>(cnt, bsum, n);
  k_scan_mid<<<1, 1024, 0, stream>>>(bsum, nb_sc);
  k_scan_apply<<<nb_sc, 256, 0, stream>>>(cnt, ptr, bsum, n, e);
  k_fillcsr<<<nb_e, 256, 0, stream>>>(row, col, ew, ptr, rank, spair, e);
  k_degdis<<<nb_n, 256, 0, stream>>>(ptr, spair, dis, n);
  k_scale<<<nb_e, 256, 0, stream>>>(spair, dis, e);

  // layer 1: combined [x@W1 -> bf16 hwb | x@pW + pb -> f32 bufR]
  k_gemmv<128, 128, 64, 4, true><<<nb_g1, 256, 0, stream>>>(x, W1, pW, pb, hwb, bufR, n);
  hipMemsetAsync(stats, 0, 128 * sizeof(float), stream);
  k_agg<<<2048, 256, 0, stream>>>(ptr, spair, dis, hwb, bufB, stats, n);
  k_bnrelu<<<nb_b, 256, 0, stream>>>(bufB, bufR, stats, g1, be1, bufA, n);

  // layer 2
  k_gemmv<64, 64, 64, 4, false><<<nb_g2, 256, 0, stream>>>(bufA, W2, nullptr, nullptr, hwb, nullptr, n);
  hipMemsetAsync(stats, 0, 128 * sizeof(float), stream);
  k_agg<<<2048, 256, 0, stream>>>(ptr, spair, dis, hwb, bufB, stats, n);
  k_bnrelu<<<nb_b, 256, 0, stream>>>(bufB, bufA, stats, g2, be2, out, n);
}

// Round 12
// 416.624 us; speedup vs baseline: 1.3297x; 1.1330x over previous
//
#include <hip/hip_runtime.h>

static constexpr float BN_EPS = 1e-5f;
typedef unsigned int uint;
typedef unsigned short ushort;
typedef __attribute__((ext_vector_type(8))) short bf16x8;
typedef __attribute__((ext_vector_type(4))) float f32x4;

__device__ __forceinline__ void fatomic_add(float* p, float v) {
  unsafeAtomicAdd(p, v);  // HW global_atomic_add_f32
}

__device__ __forceinline__ ushort f2bf(float f) {  // f32 -> bf16 RNE
  uint u = __float_as_uint(f);
  u += 0x7fffu + ((u >> 16) & 1u);
  return (ushort)(u >> 16);
}

__device__ __forceinline__ float4 bf4_decode(uint2 r) {
  return make_float4(__uint_as_float(r.x << 16), __uint_as_float(r.x & 0xffff0000u),
                     __uint_as_float(r.y << 16), __uint_as_float(r.y & 0xffff0000u));
}

// histogram keyed by col; stores each edge's arrival rank (for atomic-free fill)
__global__ void k_hist(const int* __restrict__ col, int* __restrict__ cnt,
                       int* __restrict__ rank, int e) {
  int i = blockIdx.x * 256 + threadIdx.x;
  if (i < e) rank[i] = atomicAdd(&cnt[col[i]], 1);
}

// ---- device-wide exclusive scan of cnt[n] (1024 elems/block) ----
__global__ __launch_bounds__(256) void k_scan_part(const int* __restrict__ cnt,
                                                   int* __restrict__ bsum, int n) {
  __shared__ int sm[256];
  int t = threadIdx.x;
  int base = blockIdx.x * 1024 + t * 4;
  int s = 0;
#pragma unroll
  for (int j = 0; j < 4; j++) {
    int i = base + j;
    if (i < n) s += cnt[i];
  }
  sm[t] = s;
  __syncthreads();
  for (int off = 128; off > 0; off >>= 1) {
    if (t < off) sm[t] += sm[t + off];
    __syncthreads();
  }
  if (t == 0) bsum[blockIdx.x] = sm[0];
}

__global__ __launch_bounds__(1024) void k_scan_mid(int* __restrict__ bsum, int nb) {
  __shared__ int sm[1024];
  int t = threadIdx.x;
  int v = (t < nb) ? bsum[t] : 0;
  sm[t] = v;
  __syncthreads();
  for (int off = 1; off < 1024; off <<= 1) {
    int o = (t >= off) ? sm[t - off] : 0;
    __syncthreads();
    sm[t] += o;
    __syncthreads();
  }
  if (t < nb) bsum[t] = sm[t] - v;  // exclusive block offsets
}

__global__ __launch_bounds__(256) void k_scan_apply(const int* __restrict__ cnt,
                                                    int* __restrict__ ptr,
                                                    const int* __restrict__ bsum,
                                                    int n, int e) {
  __shared__ int sm[256];
  int t = threadIdx.x;
  int base = blockIdx.x * 1024 + t * 4;
  int v[4];
  int s = 0;
#pragma unroll
  for (int j = 0; j < 4; j++) {
    int i = base + j;
    v[j] = (i < n) ? cnt[i] : 0;
    s += v[j];
  }
  sm[t] = s;
  __syncthreads();
  for (int off = 1; off < 256; off <<= 1) {
    int o = (t >= off) ? sm[t - off] : 0;
    __syncthreads();
    sm[t] += o;
    __syncthreads();
  }
  int run = bsum[blockIdx.x] + sm[t] - s;
#pragma unroll
  for (int j = 0; j < 4; j++) {
    int i = base + j;
    if (i < n) {
      ptr[i] = run;
      run += v[j];
    }
  }
  if (blockIdx.x == 0 && t == 0) ptr[n] = e;
}

// atomic-free CSR fill: slot = ptr[col] + rank
__global__ void k_fillcsr(const int* __restrict__ row, const int* __restrict__ col,
                          const float* __restrict__ ew, const int* __restrict__ ptr,
                          const int* __restrict__ rank, int2* __restrict__ spair, int e) {
  int i = blockIdx.x * 256 + threadIdx.x;
  if (i >= e) return;
  int p = ptr[col[i]] + rank[i];
  spair[p] = make_int2(row[i], __float_as_int(ew[i]));
}

// per-node: deg = 1 (self-loop) + segment-sum of ew; dis = rsqrt(deg). No atomics.
__global__ void k_degdis(const int* __restrict__ ptr, const int2* __restrict__ spair,
                         float* __restrict__ dis, int n) {
  int v = blockIdx.x * 256 + threadIdx.x;
  if (v >= n) return;
  int b = ptr[v], en = ptr[v + 1];
  float s = 1.0f;
  for (int j = b; j < en; j++) s += __int_as_float(spair[j].y);
  dis[v] = rsqrtf(s);
}

// fold dis[row] into stored edge weight (dis[col] applied in k_agg)
__global__ void k_scale(int2* __restrict__ spair, const float* __restrict__ dis, int e) {
  int i = blockIdx.x * 256 + threadIdx.x;
  if (i >= e) return;
  int2 m = spair[i];
  spair[i] = make_int2(m.x, __float_as_int(__int_as_float(m.y) * dis[m.x]));
}

// ---- aggregation v3 + fused BN stats (unchanged).
__global__ __launch_bounds__(256) void k_agg(
    const int* __restrict__ ptr, const int2* __restrict__ spair,
    const float* __restrict__ dis, const ushort* __restrict__ hwb,
    float* __restrict__ agg, float* __restrict__ stats, int n) {
  int lane = threadIdx.x & 63;
  int grp = lane >> 4;
  int li = lane & 15;
  int wid = blockIdx.x * 4 + (threadIdx.x >> 6);
  int nw = gridDim.x * 4;
  float st_s[4] = {0.f, 0.f, 0.f, 0.f};
  float st_q[4] = {0.f, 0.f, 0.f, 0.f};

  for (int vb = wid * 4; vb < n; vb += nw * 4) {
    int v = vb + grp;
    bool on = v < n;
    float4 acc = make_float4(0.f, 0.f, 0.f, 0.f);
    float d = 0.f;
    int beg = 0, end = 0;
    if (on) {
      beg = ptr[v];
      end = ptr[v + 1];
      d = dis[v];
      uint2 rs = *(const uint2*)(hwb + (size_t)v * 64 + li * 4);
      float4 f = bf4_decode(rs);
      acc = make_float4(d * f.x, d * f.y, d * f.z, d * f.w);  // self-loop (1 of 2 dis)
    }
    if (on && beg < end) {
      const int4* sp = (const int4*)spair;
      int jc = beg & ~3;           // 4-edge aligned chunk start
      int h = jc >> 1;             // int4 index of chunk
      int nch = (end - jc + 3) >> 2;
      int4 a0 = sp[h], a1 = sp[h + 1];  // meta chunk 0
      int4 b0, b1;                       // meta chunk c+1 (guarded use)
      if (nch > 1) { b0 = sp[h + 2]; b1 = sp[h + 3]; }
      float wC[4];
      uint2 gC[4];
      {
        int rr[4] = {a0.x, a0.z, a1.x, a1.z};
        int wi[4] = {a0.y, a0.w, a1.y, a1.w};
#pragma unroll
        for (int k = 0; k < 4; k++) {
          int idx = jc + k;
          bool okk = (idx >= beg) && (idx < end);
          int r = okk ? rr[k] : v;
          wC[k] = okk ? __int_as_float(wi[k]) : 0.f;
          gC[k] = *(const uint2*)(hwb + (size_t)r * 64 + li * 4);
        }
      }
      for (int c = 0; c < nch; c++) {
        float wN[4];
        uint2 gN[4];
        if (c + 1 < nch) {  // extract meta(c+1), issue its gathers
          int jn = jc + 4;
          int rr[4] = {b0.x, b0.z, b1.x, b1.z};
          int wi[4] = {b0.y, b0.w, b1.y, b1.w};
#pragma unroll
          for (int k = 0; k < 4; k++) {
            bool okk = (jn + k) < end;
            int r = okk ? rr[k] : v;
            wN[k] = okk ? __int_as_float(wi[k]) : 0.f;
            gN[k] = *(const uint2*)(hwb + (size_t)r * 64 + li * 4);
          }
        }
        if (c + 2 < nch) {  // prefetch meta(c+2)
          b0 = sp[h + 2 * (c + 2)];
          b1 = sp[h + 2 * (c + 2) + 1];
        }
#pragma unroll
        for (int k = 0; k < 4; k++) {  // compute chunk c
          float4 f = bf4_decode(gC[k]);
          acc.x = fmaf(wC[k], f.x, acc.x);
          acc.y = fmaf(wC[k], f.y, acc.y);
          acc.z = fmaf(wC[k], f.z, acc.z);
          acc.w = fmaf(wC[k], f.w, acc.w);
        }
        if (c + 1 < nch) {
#pragma unroll
          for (int k = 0; k < 4; k++) { gC[k] = gN[k]; wC[k] = wN[k]; }
        }
        jc += 4;
      }
    }
    if (on) {
      acc.x *= d; acc.y *= d; acc.z *= d; acc.w *= d;  // 2nd dis factor
      *(float4*)(agg + (size_t)v * 64 + li * 4) = acc;
      st_s[0] += acc.x; st_s[1] += acc.y; st_s[2] += acc.z; st_s[3] += acc.w;
      st_q[0] = fmaf(acc.x, acc.x, st_q[0]);
      st_q[1] = fmaf(acc.y, acc.y, st_q[1]);
      st_q[2] = fmaf(acc.z, acc.z, st_q[2]);
      st_q[3] = fmaf(acc.w, acc.w, st_q[3]);
    }
  }

#pragma unroll
  for (int j = 0; j < 4; j++) {
    st_s[j] += __shfl_xor(st_s[j], 16);
    st_s[j] += __shfl_xor(st_s[j], 32);
    st_q[j] += __shfl_xor(st_q[j], 16);
    st_q[j] += __shfl_xor(st_q[j], 32);
  }
  __shared__ float rs[4][64];
  __shared__ float rq[4][64];
  int wv = threadIdx.x >> 6;
  if (grp == 0) {
#pragma unroll
    for (int j = 0; j < 4; j++) {
      rs[wv][li * 4 + j] = st_s[j];
      rq[wv][li * 4 + j] = st_q[j];
    }
  }
  __syncthreads();
  if (threadIdx.x < 64) {
    int c = threadIdx.x;
    float s = rs[0][c] + rs[1][c] + rs[2][c] + rs[3][c];
    float q = rq[0][c] + rq[1][c] + rq[2][c] + rq[3][c];
    fatomic_add(&stats[c], s);
    fatomic_add(&stats[64 + c], q);
  }
}

// ---- GEMM1 via MFMA: [n,128] @ [128,128]. 4 waves/block; wave = 32 rows
// (2 row-tiles) x 128 cols (8 col-tiles of 16). Whole weight [W1|pW] staged
// once in LDS as bf16 WT[col][k] with XOR swizzle (byte ^= (col&7)<<4).
// mfma_f32_16x16x32_bf16 layouts: A lane holds A[l&15][8*(l>>4)+e];
// B lane holds B[8*(l>>4)+e][l&15]; D row=4*(l>>4)+e, col=l&15.
// Cols 0-63 -> bf16 hwb; cols 64-127 -> f32 residual + pb.
__global__ __launch_bounds__(256) void k_gemm1m(
    const float* __restrict__ x, const float* __restrict__ W1,
    const float* __restrict__ pW, const float* __restrict__ pb,
    ushort* __restrict__ ob, float* __restrict__ of, int n) {
  __shared__ ushort wT[128 * 128];  // 32 KB
  int tid = threadIdx.x;
  for (int idx = tid; idx < 128 * 64; idx += 256) {
    int c = idx >> 6;        // output col 0..127
    int kp = idx & 63;       // k pair: k = 2*kp, 2*kp+1
    const float* src = (c < 64) ? (W1 + c) : (pW + (c - 64));
    float f0 = src[(size_t)(2 * kp) * 64];
    float f1 = src[(size_t)(2 * kp + 1) * 64];
    uint pk = (uint)f2bf(f0) | ((uint)f2bf(f1) << 16);
    int byte = c * 256 + kp * 4;
    byte ^= ((c & 7) << 4);
    *(uint*)((char*)wT + byte) = pk;
  }
  __syncthreads();

  int lane = tid & 63;
  int wv = tid >> 6;
  int lr = lane & 15;   // A-row / B-col / D-col within tile
  int lk = lane >> 4;   // k sub-block 0..3
  int rowBase = blockIdx.x * 128 + wv * 32;

  f32x4 acc[2][8];
#pragma unroll
  for (int i = 0; i < 2; i++)
#pragma unroll
    for (int j = 0; j < 8; j++) acc[i][j] = (f32x4){0.f, 0.f, 0.f, 0.f};

  int r0 = rowBase + lr;
  int r1 = rowBase + 16 + lr;
  bool ok0 = r0 < n, ok1 = r1 < n;
  int swz = (lr & 7) << 4;

#pragma unroll
  for (int ks = 0; ks < 4; ks++) {
    int k0 = ks * 32 + lk * 8;
    bf16x8 a0 = (bf16x8)(short)0, a1 = (bf16x8)(short)0;
    if (ok0) {
      const float4* xp = (const float4*)(x + (size_t)r0 * 128 + k0);
      float4 v0 = xp[0], v1 = xp[1];
      a0[0] = (short)f2bf(v0.x); a0[1] = (short)f2bf(v0.y);
      a0[2] = (short)f2bf(v0.z); a0[3] = (short)f2bf(v0.w);
      a0[4] = (short)f2bf(v1.x); a0[5] = (short)f2bf(v1.y);
      a0[6] = (short)f2bf(v1.z); a0[7] = (short)f2bf(v1.w);
    }
    if (ok1) {
      const float4* xp = (const float4*)(x + (size_t)r1 * 128 + k0);
      float4 v0 = xp[0], v1 = xp[1];
      a1[0] = (short)f2bf(v0.x); a1[1] = (short)f2bf(v0.y);
      a1[2] = (short)f2bf(v0.z); a1[3] = (short)f2bf(v0.w);
      a1[4] = (short)f2bf(v1.x); a1[5] = (short)f2bf(v1.y);
      a1[6] = (short)f2bf(v1.z); a1[7] = (short)f2bf(v1.w);
    }
#pragma unroll
    for (int ct = 0; ct < 8; ct++) {
      int byte = ((ct * 16 + lr) * 128 + k0) * 2;
      byte ^= swz;
      bf16x8 b = *(const bf16x8*)((const char*)wT + byte);
      acc[0][ct] = __builtin_amdgcn_mfma_f32_16x16x32_bf16(a0, b, acc[0][ct], 0, 0, 0);
      acc[1][ct] = __builtin_amdgcn_mfma_f32_16x16x32_bf16(a1, b, acc[1][ct], 0, 0, 0);
    }
  }

  // bias values for the residual half (cols 64-127): c = (ct-4)*16 + lr
  float bias[4];
#pragma unroll
  for (int q = 0; q < 4; q++) bias[q] = pb[q * 16 + lr];

#pragma unroll
  for (int rt = 0; rt < 2; rt++) {
#pragma unroll
    for (int e = 0; e < 4; e++) {
      int r = rowBase + rt * 16 + lk * 4 + e;
      if (r >= n) continue;
#pragma unroll
      for (int ct = 0; ct < 4; ct++)
        ob[(size_t)r * 64 + ct * 16 + lr] = f2bf(acc[rt][ct][e]);
#pragma unroll
      for (int ct = 4; ct < 8; ct++)
        of[(size_t)r * 64 + (ct - 4) * 16 + lr] = acc[rt][ct][e] + bias[ct - 4];
    }
  }
}

// ---- GEMM2 via MFMA: [n,64] @ [64,64] -> bf16 hwb. Same structure, K=64 (2
// k-steps), 4 col-tiles. Input h is f32, converted in-register.
__global__ __launch_bounds__(256) void k_gemm2m(
    const float* __restrict__ h, const float* __restrict__ W2,
    ushort* __restrict__ ob, int n) {
  __shared__ ushort wT[64 * 64];  // 8 KB
  int tid = threadIdx.x;
  for (int idx = tid; idx < 64 * 32; idx += 256) {
    int c = idx >> 5;        // col 0..63
    int kp = idx & 31;       // k pair
    float f0 = W2[(size_t)(2 * kp) * 64 + c];
    float f1 = W2[(size_t)(2 * kp + 1) * 64 + c];
    uint pk = (uint)f2bf(f0) | ((uint)f2bf(f1) << 16);
    int byte = c * 128 + kp * 4;
    byte ^= ((c & 7) << 4);
    *(uint*)((char*)wT + byte) = pk;
  }
  __syncthreads();

  int lane = tid & 63;
  int wv = tid >> 6;
  int lr = lane & 15;
  int lk = lane >> 4;
  int rowBase = blockIdx.x * 128 + wv * 32;

  f32x4 acc[2][4];
#pragma unroll
  for (int i = 0; i < 2; i++)
#pragma unroll
    for (int j = 0; j < 4; j++) acc[i][j] = (f32x4){0.f, 0.f, 0.f, 0.f};

  int r0 = rowBase + lr;
  int r1 = rowBase + 16 + lr;
  bool ok0 = r0 < n, ok1 = r1 < n;
  int swz = (lr & 7) << 4;

#pragma unroll
  for (int ks = 0; ks < 2; ks++) {
    int k0 = ks * 32 + lk * 8;
    bf16x8 a0 = (bf16x8)(short)0, a1 = (bf16x8)(short)0;
    if (ok0) {
      const float4* xp = (const float4*)(h + (size_t)r0 * 64 + k0);
      float4 v0 = xp[0], v1 = xp[1];
      a0[0] = (short)f2bf(v0.x); a0[1] = (short)f2bf(v0.y);
      a0[2] = (short)f2bf(v0.z); a0[3] = (short)f2bf(v0.w);
      a0[4] = (short)f2bf(v1.x); a0[5] = (short)f2bf(v1.y);
      a0[6] = (short)f2bf(v1.z); a0[7] = (short)f2bf(v1.w);
    }
    if (ok1) {
      const float4* xp = (const float4*)(h + (size_t)r1 * 64 + k0);
      float4 v0 = xp[0], v1 = xp[1];
      a1[0] = (short)f2bf(v0.x); a1[1] = (short)f2bf(v0.y);
      a1[2] = (short)f2bf(v0.z); a1[3] = (short)f2bf(v0.w);
      a1[4] = (short)f2bf(v1.x); a1[5] = (short)f2bf(v1.y);
      a1[6] = (short)f2bf(v1.z); a1[7] = (short)f2bf(v1.w);
    }
#pragma unroll
    for (int ct = 0; ct < 4; ct++) {
      int byte = ((ct * 16 + lr) * 64 + k0) * 2;
      byte ^= swz;
      bf16x8 b = *(const bf16x8*)((const char*)wT + byte);
      acc[0][ct] = __builtin_amdgcn_mfma_f32_16x16x32_bf16(a0, b, acc[0][ct], 0, 0, 0);
      acc[1][ct] = __builtin_amdgcn_mfma_f32_16x16x32_bf16(a1, b, acc[1][ct], 0, 0, 0);
    }
  }

#pragma unroll
  for (int rt = 0; rt < 2; rt++) {
#pragma unroll
    for (int e = 0; e < 4; e++) {
      int r = rowBase + rt * 16 + lk * 4 + e;
      if (r >= n) continue;
#pragma unroll
      for (int ct = 0; ct < 4; ct++)
        ob[(size_t)r * 64 + ct * 16 + lr] = f2bf(acc[rt][ct][e]);
    }
  }
}

// out = relu(g*(agg-mu)*rsqrt(var+eps)+beta) + res   (conv bias cancels in BN)
__global__ __launch_bounds__(256) void k_bnrelu(
    const float* __restrict__ agg, const float* __restrict__ res,
    const float* __restrict__ stats, const float* __restrict__ g,
    const float* __restrict__ beta, float* __restrict__ out, int n) {
  int idx = blockIdx.x * 256 + threadIdx.x;
  if (idx >= n * 16) return;
  int c4 = (idx & 15) * 4;
  float invN = 1.0f / (float)n;
  float4 a = ((const float4*)agg)[idx];
  float4 rr = ((const float4*)res)[idx];
  float av[4] = {a.x, a.y, a.z, a.w};
  float rv[4] = {rr.x, rr.y, rr.z, rr.w};
  float vo[4];
#pragma unroll
  for (int j = 0; j < 4; j++) {
    int c = c4 + j;
    float mu = stats[c] * invN;
    float var = stats[64 + c] * invN - mu * mu;
    float sc = g[c] * rsqrtf(var + BN_EPS);
    float v = (av[j] - mu) * sc + beta[c];
    vo[j] = fmaxf(v, 0.0f) + rv[j];
  }
  ((float4*)out)[idx] = make_float4(vo[0], vo[1], vo[2], vo[3]);
}

extern "C" void kernel_launch(void* const* d_in, const int* in_sizes, int n_in,
                              void* d_out, int out_size, void* d_ws, size_t ws_size,
                              hipStream_t stream) {
  const float* x = (const float*)d_in[0];
  const int* ei = (const int*)d_in[1];
  const float* ew = (const float*)d_in[2];
  const float* W1 = (const float*)d_in[3];
  const float* g1 = (const float*)d_in[5];
  const float* be1 = (const float*)d_in[6];
  const float* W2 = (const float*)d_in[7];
  const float* g2 = (const float*)d_in[9];
  const float* be2 = (const float*)d_in[10];
  const float* pW = (const float*)d_in[11];
  const float* pb = (const float*)d_in[12];

  int n = in_sizes[0] / 128;
  int e = in_sizes[1] / 2;
  const int* row = ei;      // source
  const int* col = ei + e;  // target

  // workspace layout (spair padded by 16 int2: chunked k_agg may over-READ
  // up to 3 entries past e; masked before use)
  float* ws = (float*)d_ws;
  float* dis = ws;                             // n
  int* ptr = (int*)(dis + n);                  // n+4
  int* cnt = ptr + n + 4;                      // n
  int* rank = cnt + n;                         // e
  int* bsum = rank + e;                        // 1024
  int2* spair = (int2*)(bsum + 1024);          // e int2 (+16 pad)
  ushort* hwb = (ushort*)(spair + e + 16);     // n*64 bf16 (hw1, then hw2)
  float* bufR = (float*)(hwb + (size_t)n * 64);  // n*64 (residual)
  float* bufB = bufR + (size_t)n * 64;         // n*64 (agg)
  float* bufA = bufB + (size_t)n * 64;         // n*64 (h)
  float* stats = bufA + (size_t)n * 64;        // 128

  float* out = (float*)d_out;

  int nb_n = (n + 255) / 256;
  int nb_e = (e + 255) / 256;
  int nb_b = (n * 16 + 255) / 256;
  int nb_sc = (n + 1023) / 1024;
  int nb_g = (n + 127) / 128;  // 128 rows/block for both MFMA GEMMs

  // CSR build + gcn_norm
  hipMemsetAsync(cnt, 0, n * sizeof(int), stream);
  k_hist<<<nb_e, 256, 0, stream>>>(col, cnt, rank, e);
  k_scan_part<<<nb_sc, 256, 0, stream>>>(cnt, bsum, n);
  k_scan_mid<<<1, 1024, 0, stream>>>(bsum, nb_sc);
  k_scan_apply<<<nb_sc, 256, 0, stream>>>(cnt, ptr, bsum, n, e);
  k_fillcsr<<<nb_e, 256, 0, stream>>>(row, col, ew, ptr, rank, spair, e);
  k_degdis<<<nb_n, 256, 0, stream>>>(ptr, spair, dis, n);
  k_scale<<<nb_e, 256, 0, stream>>>(spair, dis, e);

  // layer 1: combined [x@W1 -> bf16 hwb | x@pW + pb -> f32 bufR]
  k_gemm1m<<<nb_g, 256, 0, stream>>>(x, W1, pW, pb, hwb, bufR, n);
  hipMemsetAsync(stats, 0, 128 * sizeof(float), stream);
  k_agg<<<2048, 256, 0, stream>>>(ptr, spair, dis, hwb, bufB, stats, n);
  k_bnrelu<<<nb_b, 256, 0, stream>>>(bufB, bufR, stats, g1, be1, bufA, n);

  // layer 2
  k_gemm2m<<<nb_g, 256, 0, stream>>>(bufA, W2, hwb, n);
  hipMemsetAsync(stats, 0, 128 * sizeof(float), stream);
  k_agg<<<2048, 256, 0, stream>>>(ptr, spair, dis, hwb, bufB, stats, n);
  k_bnrelu<<<nb_b, 256, 0, stream>>>(bufB, bufA, stats, g2, be2, out, n);
}

// Round 13
// 409.443 us; speedup vs baseline: 1.3530x; 1.0175x over previous
//
#include <hip/hip_runtime.h>

static constexpr float BN_EPS = 1e-5f;
typedef unsigned int uint;
typedef unsigned short ushort;
typedef __attribute__((ext_vector_type(8))) short bf16x8;
typedef __attribute__((ext_vector_type(4))) float f32x4;

__device__ __forceinline__ void fatomic_add(float* p, float v) {
  unsafeAtomicAdd(p, v);  // HW global_atomic_add_f32
}

__device__ __forceinline__ ushort f2bf(float f) {  // f32 -> bf16 RNE
  uint u = __float_as_uint(f);
  u += 0x7fffu + ((u >> 16) & 1u);
  return (ushort)(u >> 16);
}

__device__ __forceinline__ float4 bf4_decode(uint2 r) {
  return make_float4(__uint_as_float(r.x << 16), __uint_as_float(r.x & 0xffff0000u),
                     __uint_as_float(r.y << 16), __uint_as_float(r.y & 0xffff0000u));
}

// histogram keyed by col; stores each edge's arrival rank (for atomic-free fill)
__global__ void k_hist(const int* __restrict__ col, int* __restrict__ cnt,
                       int* __restrict__ rank, int e) {
  int i = blockIdx.x * 256 + threadIdx.x;
  if (i < e) rank[i] = atomicAdd(&cnt[col[i]], 1);
}

// ---- device-wide exclusive scan of cnt[n] (1024 elems/block) ----
__global__ __launch_bounds__(256) void k_scan_part(const int* __restrict__ cnt,
                                                   int* __restrict__ bsum, int n) {
  __shared__ int sm[256];
  int t = threadIdx.x;
  int base = blockIdx.x * 1024 + t * 4;
  int s = 0;
#pragma unroll
  for (int j = 0; j < 4; j++) {
    int i = base + j;
    if (i < n) s += cnt[i];
  }
  sm[t] = s;
  __syncthreads();
  for (int off = 128; off > 0; off >>= 1) {
    if (t < off) sm[t] += sm[t + off];
    __syncthreads();
  }
  if (t == 0) bsum[blockIdx.x] = sm[0];
}

__global__ __launch_bounds__(1024) void k_scan_mid(int* __restrict__ bsum, int nb) {
  __shared__ int sm[1024];
  int t = threadIdx.x;
  int v = (t < nb) ? bsum[t] : 0;
  sm[t] = v;
  __syncthreads();
  for (int off = 1; off < 1024; off <<= 1) {
    int o = (t >= off) ? sm[t - off] : 0;
    __syncthreads();
    sm[t] += o;
    __syncthreads();
  }
  if (t < nb) bsum[t] = sm[t] - v;  // exclusive block offsets
}

__global__ __launch_bounds__(256) void k_scan_apply(const int* __restrict__ cnt,
                                                    int* __restrict__ ptr,
                                                    const int* __restrict__ bsum,
                                                    int n, int e) {
  __shared__ int sm[256];
  int t = threadIdx.x;
  int base = blockIdx.x * 1024 + t * 4;
  int v[4];
  int s = 0;
#pragma unroll
  for (int j = 0; j < 4; j++) {
    int i = base + j;
    v[j] = (i < n) ? cnt[i] : 0;
    s += v[j];
  }
  sm[t] = s;
  __syncthreads();
  for (int off = 1; off < 256; off <<= 1) {
    int o = (t >= off) ? sm[t - off] : 0;
    __syncthreads();
    sm[t] += o;
    __syncthreads();
  }
  int run = bsum[blockIdx.x] + sm[t] - s;
#pragma unroll
  for (int j = 0; j < 4; j++) {
    int i = base + j;
    if (i < n) {
      ptr[i] = run;
      run += v[j];
    }
  }
  if (blockIdx.x == 0 && t == 0) ptr[n] = e;
}

// atomic-free CSR fill: slot = ptr[col] + rank
__global__ void k_fillcsr(const int* __restrict__ row, const int* __restrict__ col,
                          const float* __restrict__ ew, const int* __restrict__ ptr,
                          const int* __restrict__ rank, int2* __restrict__ spair, int e) {
  int i = blockIdx.x * 256 + threadIdx.x;
  if (i >= e) return;
  int p = ptr[col[i]] + rank[i];
  spair[p] = make_int2(row[i], __float_as_int(ew[i]));
}

// per-node: deg = 1 (self-loop) + segment-sum of ew; dis = rsqrt(deg). No atomics.
__global__ void k_degdis(const int* __restrict__ ptr, const int2* __restrict__ spair,
                         float* __restrict__ dis, int n) {
  int v = blockIdx.x * 256 + threadIdx.x;
  if (v >= n) return;
  int b = ptr[v], en = ptr[v + 1];
  float s = 1.0f;
  for (int j = b; j < en; j++) s += __int_as_float(spair[j].y);
  dis[v] = rsqrtf(s);
}

// fold dis[row] into stored edge weight (dis[col] applied in k_agg)
__global__ void k_scale(int2* __restrict__ spair, const float* __restrict__ dis, int e) {
  int i = blockIdx.x * 256 + threadIdx.x;
  if (i >= e) return;
  int2 m = spair[i];
  spair[i] = make_int2(m.x, __float_as_int(__int_as_float(m.y) * dis[m.x]));
}

// ---- aggregation v4 + fused BN stats.
// One NODE per 16-lane group (4 nodes/wave). 4-edge aligned chunks with a
// DEPTH-3 pipeline: while computing chunk c, gathers for chunks c+1 and c+2
// are in flight (12 outstanding row-gathers/group) and meta for c+3 loads.
// Head/tail lanes masked (weight 0, row -> v) so no OOB gather addresses.
__global__ __launch_bounds__(256) void k_agg(
    const int* __restrict__ ptr, const int2* __restrict__ spair,
    const float* __restrict__ dis, const ushort* __restrict__ hwb,
    float* __restrict__ agg, float* __restrict__ stats, int n) {
  int lane = threadIdx.x & 63;
  int grp = lane >> 4;
  int li = lane & 15;
  int wid = blockIdx.x * 4 + (threadIdx.x >> 6);
  int nw = gridDim.x * 4;
  float st_s[4] = {0.f, 0.f, 0.f, 0.f};
  float st_q[4] = {0.f, 0.f, 0.f, 0.f};

  for (int vb = wid * 4; vb < n; vb += nw * 4) {
    int v = vb + grp;
    bool on = v < n;
    float4 acc = make_float4(0.f, 0.f, 0.f, 0.f);
    float d = 0.f;
    int beg = 0, end = 0;
    if (on) {
      beg = ptr[v];
      end = ptr[v + 1];
      d = dis[v];
      uint2 rs = *(const uint2*)(hwb + (size_t)v * 64 + li * 4);
      float4 f = bf4_decode(rs);
      acc = make_float4(d * f.x, d * f.y, d * f.z, d * f.w);  // self-loop (1 of 2 dis)
    }
    if (on && beg < end) {
      const int4* sp = (const int4*)spair;
      int jc = beg & ~3;           // 4-edge aligned chunk start
      int h = jc >> 1;             // int4 index of chunk 0
      int nch = (end - jc + 3) >> 2;

      // meta/gather slots A (chunk c), B (c+1), C (c+2); explicit rotation.
      float wA[4], wB[4], wC_[4];
      uint2 gA[4], gB[4], gC_[4];
      int4 mN0, mN1;  // meta for the NEXT chunk to issue (c+3)

      // prologue: extract meta + issue gathers for chunks 0,1,2 (guarded)
      {
        int4 p0 = sp[h], p1 = sp[h + 1];
        int rr[4] = {p0.x, p0.z, p1.x, p1.z};
        int wi[4] = {p0.y, p0.w, p1.y, p1.w};
#pragma unroll
        for (int k = 0; k < 4; k++) {
          int idx = jc + k;
          bool okk = (idx >= beg) && (idx < end);
          int r = okk ? rr[k] : v;
          wA[k] = okk ? __int_as_float(wi[k]) : 0.f;
          gA[k] = *(const uint2*)(hwb + (size_t)r * 64 + li * 4);
        }
      }
      if (nch > 1) {
        int4 p0 = sp[h + 2], p1 = sp[h + 3];
        int rr[4] = {p0.x, p0.z, p1.x, p1.z};
        int wi[4] = {p0.y, p0.w, p1.y, p1.w};
#pragma unroll
        for (int k = 0; k < 4; k++) {
          bool okk = (jc + 4 + k) < end;
          int r = okk ? rr[k] : v;
          wB[k] = okk ? __int_as_float(wi[k]) : 0.f;
          gB[k] = *(const uint2*)(hwb + (size_t)r * 64 + li * 4);
        }
      }
      if (nch > 2) {
        int4 p0 = sp[h + 4], p1 = sp[h + 5];
        int rr[4] = {p0.x, p0.z, p1.x, p1.z};
        int wi[4] = {p0.y, p0.w, p1.y, p1.w};
#pragma unroll
        for (int k = 0; k < 4; k++) {
          bool okk = (jc + 8 + k) < end;
          int r = okk ? rr[k] : v;
          wC_[k] = okk ? __int_as_float(wi[k]) : 0.f;
          gC_[k] = *(const uint2*)(hwb + (size_t)r * 64 + li * 4);
        }
      }
      if (nch > 3) { mN0 = sp[h + 6]; mN1 = sp[h + 7]; }

      for (int c = 0; c < nch; c++) {
        // issue gathers for chunk c+3 into fresh slot (will rotate into C)
        float wD[4];
        uint2 gD[4];
        if (c + 3 < nch) {
          int jn = jc + 12;
          int rr[4] = {mN0.x, mN0.z, mN1.x, mN1.z};
          int wi[4] = {mN0.y, mN0.w, mN1.y, mN1.w};
#pragma unroll
          for (int k = 0; k < 4; k++) {
            bool okk = (jn + k) < end;
            int r = okk ? rr[k] : v;
            wD[k] = okk ? __int_as_float(wi[k]) : 0.f;
            gD[k] = *(const uint2*)(hwb + (size_t)r * 64 + li * 4);
          }
        }
        if (c + 4 < nch) {  // prefetch meta for chunk c+4
          mN0 = sp[h + 2 * (c + 4)];
          mN1 = sp[h + 2 * (c + 4) + 1];
        }
        // compute chunk c (slot A)
#pragma unroll
        for (int k = 0; k < 4; k++) {
          float4 f = bf4_decode(gA[k]);
          acc.x = fmaf(wA[k], f.x, acc.x);
          acc.y = fmaf(wA[k], f.y, acc.y);
          acc.z = fmaf(wA[k], f.z, acc.z);
          acc.w = fmaf(wA[k], f.w, acc.w);
        }
        // rotate A <- B <- C <- D
#pragma unroll
        for (int k = 0; k < 4; k++) {
          gA[k] = gB[k]; wA[k] = wB[k];
          gB[k] = gC_[k]; wB[k] = wC_[k];
        }
        if (c + 3 < nch) {
#pragma unroll
          for (int k = 0; k < 4; k++) { gC_[k] = gD[k]; wC_[k] = wD[k]; }
        }
        jc += 4;
      }
    }
    if (on) {
      acc.x *= d; acc.y *= d; acc.z *= d; acc.w *= d;  // 2nd dis factor
      *(float4*)(agg + (size_t)v * 64 + li * 4) = acc;
      st_s[0] += acc.x; st_s[1] += acc.y; st_s[2] += acc.z; st_s[3] += acc.w;
      st_q[0] = fmaf(acc.x, acc.x, st_q[0]);
      st_q[1] = fmaf(acc.y, acc.y, st_q[1]);
      st_q[2] = fmaf(acc.z, acc.z, st_q[2]);
      st_q[3] = fmaf(acc.w, acc.w, st_q[3]);
    }
  }

#pragma unroll
  for (int j = 0; j < 4; j++) {
    st_s[j] += __shfl_xor(st_s[j], 16);
    st_s[j] += __shfl_xor(st_s[j], 32);
    st_q[j] += __shfl_xor(st_q[j], 16);
    st_q[j] += __shfl_xor(st_q[j], 32);
  }
  __shared__ float rs[4][64];
  __shared__ float rq[4][64];
  int wv = threadIdx.x >> 6;
  if (grp == 0) {
#pragma unroll
    for (int j = 0; j < 4; j++) {
      rs[wv][li * 4 + j] = st_s[j];
      rq[wv][li * 4 + j] = st_q[j];
    }
  }
  __syncthreads();
  if (threadIdx.x < 64) {
    int c = threadIdx.x;
    float s = rs[0][c] + rs[1][c] + rs[2][c] + rs[3][c];
    float q = rq[0][c] + rq[1][c] + rq[2][c] + rq[3][c];
    fatomic_add(&stats[c], s);
    fatomic_add(&stats[64 + c], q);
  }
}

// ---- GEMM1 via MFMA: [n,128] @ [128,128]. (unchanged from R12)
__global__ __launch_bounds__(256) void k_gemm1m(
    const float* __restrict__ x, const float* __restrict__ W1,
    const float* __restrict__ pW, const float* __restrict__ pb,
    ushort* __restrict__ ob, float* __restrict__ of, int n) {
  __shared__ ushort wT[128 * 128];  // 32 KB
  int tid = threadIdx.x;
  for (int idx = tid; idx < 128 * 64; idx += 256) {
    int c = idx >> 6;
    int kp = idx & 63;
    const float* src = (c < 64) ? (W1 + c) : (pW + (c - 64));
    float f0 = src[(size_t)(2 * kp) * 64];
    float f1 = src[(size_t)(2 * kp + 1) * 64];
    uint pk = (uint)f2bf(f0) | ((uint)f2bf(f1) << 16);
    int byte = c * 256 + kp * 4;
    byte ^= ((c & 7) << 4);
    *(uint*)((char*)wT + byte) = pk;
  }
  __syncthreads();

  int lane = tid & 63;
  int wv = tid >> 6;
  int lr = lane & 15;
  int lk = lane >> 4;
  int rowBase = blockIdx.x * 128 + wv * 32;

  f32x4 acc[2][8];
#pragma unroll
  for (int i = 0; i < 2; i++)
#pragma unroll
    for (int j = 0; j < 8; j++) acc[i][j] = (f32x4){0.f, 0.f, 0.f, 0.f};

  int r0 = rowBase + lr;
  int r1 = rowBase + 16 + lr;
  bool ok0 = r0 < n, ok1 = r1 < n;
  int swz = (lr & 7) << 4;

#pragma unroll
  for (int ks = 0; ks < 4; ks++) {
    int k0 = ks * 32 + lk * 8;
    bf16x8 a0 = (bf16x8)(short)0, a1 = (bf16x8)(short)0;
    if (ok0) {
      const float4* xp = (const float4*)(x + (size_t)r0 * 128 + k0);
      float4 v0 = xp[0], v1 = xp[1];
      a0[0] = (short)f2bf(v0.x); a0[1] = (short)f2bf(v0.y);
      a0[2] = (short)f2bf(v0.z); a0[3] = (short)f2bf(v0.w);
      a0[4] = (short)f2bf(v1.x); a0[5] = (short)f2bf(v1.y);
      a0[6] = (short)f2bf(v1.z); a0[7] = (short)f2bf(v1.w);
    }
    if (ok1) {
      const float4* xp = (const float4*)(x + (size_t)r1 * 128 + k0);
      float4 v0 = xp[0], v1 = xp[1];
      a1[0] = (short)f2bf(v0.x); a1[1] = (short)f2bf(v0.y);
      a1[2] = (short)f2bf(v0.z); a1[3] = (short)f2bf(v0.w);
      a1[4] = (short)f2bf(v1.x); a1[5] = (short)f2bf(v1.y);
      a1[6] = (short)f2bf(v1.z); a1[7] = (short)f2bf(v1.w);
    }
#pragma unroll
    for (int ct = 0; ct < 8; ct++) {
      int byte = ((ct * 16 + lr) * 128 + k0) * 2;
      byte ^= swz;
      bf16x8 b = *(const bf16x8*)((const char*)wT + byte);
      acc[0][ct] = __builtin_amdgcn_mfma_f32_16x16x32_bf16(a0, b, acc[0][ct], 0, 0, 0);
      acc[1][ct] = __builtin_amdgcn_mfma_f32_16x16x32_bf16(a1, b, acc[1][ct], 0, 0, 0);
    }
  }

  float bias[4];
#pragma unroll
  for (int q = 0; q < 4; q++) bias[q] = pb[q * 16 + lr];

#pragma unroll
  for (int rt = 0; rt < 2; rt++) {
#pragma unroll
    for (int e = 0; e < 4; e++) {
      int r = rowBase + rt * 16 + lk * 4 + e;
      if (r >= n) continue;
#pragma unroll
      for (int ct = 0; ct < 4; ct++)
        ob[(size_t)r * 64 + ct * 16 + lr] = f2bf(acc[rt][ct][e]);
#pragma unroll
      for (int ct = 4; ct < 8; ct++)
        of[(size_t)r * 64 + (ct - 4) * 16 + lr] = acc[rt][ct][e] + bias[ct - 4];
    }
  }
}

// ---- GEMM2 via MFMA: [n,64] @ [64,64] -> bf16 hwb. (unchanged from R12)
__global__ __launch_bounds__(256) void k_gemm2m(
    const float* __restrict__ h, const float* __restrict__ W2,
    ushort* __restrict__ ob, int n) {
  __shared__ ushort wT[64 * 64];  // 8 KB
  int tid = threadIdx.x;
  for (int idx = tid; idx < 64 * 32; idx += 256) {
    int c = idx >> 5;
    int kp = idx & 31;
    float f0 = W2[(size_t)(2 * kp) * 64 + c];
    float f1 = W2[(size_t)(2 * kp + 1) * 64 + c];
    uint pk = (uint)f2bf(f0) | ((uint)f2bf(f1) << 16);
    int byte = c * 128 + kp * 4;
    byte ^= ((c & 7) << 4);
    *(uint*)((char*)wT + byte) = pk;
  }
  __syncthreads();

  int lane = tid & 63;
  int wv = tid >> 6;
  int lr = lane & 15;
  int lk = lane >> 4;
  int rowBase = blockIdx.x * 128 + wv * 32;

  f32x4 acc[2][4];
#pragma unroll
  for (int i = 0; i < 2; i++)
#pragma unroll
    for (int j = 0; j < 4; j++) acc[i][j] = (f32x4){0.f, 0.f, 0.f, 0.f};

  int r0 = rowBase + lr;
  int r1 = rowBase + 16 + lr;
  bool ok0 = r0 < n, ok1 = r1 < n;
  int swz = (lr & 7) << 4;

#pragma unroll
  for (int ks = 0; ks < 2; ks++) {
    int k0 = ks * 32 + lk * 8;
    bf16x8 a0 = (bf16x8)(short)0, a1 = (bf16x8)(short)0;
    if (ok0) {
      const float4* xp = (const float4*)(h + (size_t)r0 * 64 + k0);
      float4 v0 = xp[0], v1 = xp[1];
      a0[0] = (short)f2bf(v0.x); a0[1] = (short)f2bf(v0.y);
      a0[2] = (short)f2bf(v0.z); a0[3] = (short)f2bf(v0.w);
      a0[4] = (short)f2bf(v1.x); a0[5] = (short)f2bf(v1.y);
      a0[6] = (short)f2bf(v1.z); a0[7] = (short)f2bf(v1.w);
    }
    if (ok1) {
      const float4* xp = (const float4*)(h + (size_t)r1 * 64 + k0);
      float4 v0 = xp[0], v1 = xp[1];
      a1[0] = (short)f2bf(v0.x); a1[1] = (short)f2bf(v0.y);
      a1[2] = (short)f2bf(v0.z); a1[3] = (short)f2bf(v0.w);
      a1[4] = (short)f2bf(v1.x); a1[5] = (short)f2bf(v1.y);
      a1[6] = (short)f2bf(v1.z); a1[7] = (short)f2bf(v1.w);
    }
#pragma unroll
    for (int ct = 0; ct < 4; ct++) {
      int byte = ((ct * 16 + lr) * 64 + k0) * 2;
      byte ^= swz;
      bf16x8 b = *(const bf16x8*)((const char*)wT + byte);
      acc[0][ct] = __builtin_amdgcn_mfma_f32_16x16x32_bf16(a0, b, acc[0][ct], 0, 0, 0);
      acc[1][ct] = __builtin_amdgcn_mfma_f32_16x16x32_bf16(a1, b, acc[1][ct], 0, 0, 0);
    }
  }

#pragma unroll
  for (int rt = 0; rt < 2; rt++) {
#pragma unroll
    for (int e = 0; e < 4; e++) {
      int r = rowBase + rt * 16 + lk * 4 + e;
      if (r >= n) continue;
#pragma unroll
      for (int ct = 0; ct < 4; ct++)
        ob[(size_t)r * 64 + ct * 16 + lr] = f2bf(acc[rt][ct][e]);
    }
  }
}

// out = relu(g*(agg-mu)*rsqrt(var+eps)+beta) + res   (conv bias cancels in BN)
__global__ __launch_bounds__(256) void k_bnrelu(
    const float* __restrict__ agg, const float* __restrict__ res,
    const float* __restrict__ stats, const float* __restrict__ g,
    const float* __restrict__ beta, float* __restrict__ out, int n) {
  int idx = blockIdx.x * 256 + threadIdx.x;
  if (idx >= n * 16) return;
  int c4 = (idx & 15) * 4;
  float invN = 1.0f / (float)n;
  float4 a = ((const float4*)agg)[idx];
  float4 rr = ((const float4*)res)[idx];
  float av[4] = {a.x, a.y, a.z, a.w};
  float rv[4] = {rr.x, rr.y, rr.z, rr.w};
  float vo[4];
#pragma unroll
  for (int j = 0; j < 4; j++) {
    int c = c4 + j;
    float mu = stats[c] * invN;
    float var = stats[64 + c] * invN - mu * mu;
    float sc = g[c] * rsqrtf(var + BN_EPS);
    float v = (av[j] - mu) * sc + beta[c];
    vo[j] = fmaxf(v, 0.0f) + rv[j];
  }
  ((float4*)out)[idx] = make_float4(vo[0], vo[1], vo[2], vo[3]);
}

extern "C" void kernel_launch(void* const* d_in, const int* in_sizes, int n_in,
                              void* d_out, int out_size, void* d_ws, size_t ws_size,
                              hipStream_t stream) {
  const float* x = (const float*)d_in[0];
  const int* ei = (const int*)d_in[1];
  const float* ew = (const float*)d_in[2];
  const float* W1 = (const float*)d_in[3];
  const float* g1 = (const float*)d_in[5];
  const float* be1 = (const float*)d_in[6];
  const float* W2 = (const float*)d_in[7];
  const float* g2 = (const float*)d_in[9];
  const float* be2 = (const float*)d_in[10];
  const float* pW = (const float*)d_in[11];
  const float* pb = (const float*)d_in[12];

  int n = in_sizes[0] / 128;
  int e = in_sizes[1] / 2;
  const int* row = ei;      // source
  const int* col = ei + e;  // target

  // workspace layout (spair padded by 32 int2: depth-3 k_agg may over-READ
  // meta up to 3 chunks past a node's list; masked before use)
  float* ws = (float*)d_ws;
  float* dis = ws;                             // n
  int* ptr = (int*)(dis + n);                  // n+4
  int* cnt = ptr + n + 4;                      // n
  int* rank = cnt + n;                         // e
  int* bsum = rank + e;                        // 1024
  int2* spair = (int2*)(bsum + 1024);          // e int2 (+32 pad)
  ushort* hwb = (ushort*)(spair + e + 32);     // n*64 bf16 (hw1, then hw2)
  float* bufR = (float*)(hwb + (size_t)n * 64);  // n*64 (residual)
  float* bufB = bufR + (size_t)n * 64;         // n*64 (agg)
  float* bufA = bufB + (size_t)n * 64;         // n*64 (h)
  float* stats = bufA + (size_t)n * 64;        // 128

  float* out = (float*)d_out;

  int nb_n = (n + 255) / 256;
  int nb_e = (e + 255) / 256;
  int nb_b = (n * 16 + 255) / 256;
  int nb_sc = (n + 1023) / 1024;
  int nb_g = (n + 127) / 128;

  // CSR build + gcn_norm
  hipMemsetAsync(cnt, 0, n * sizeof(int), stream);
  k_hist<<<nb_e, 256, 0, stream>>>(col, cnt, rank, e);
  k_scan_part<<<nb_sc, 256, 0, stream>>>(cnt, bsum, n);
  k_scan_mid<<<1, 1024, 0, stream>>>(bsum, nb_sc);
  k_scan_apply<<<nb_sc, 256, 0, stream>>>(cnt, ptr, bsum, n, e);
  k_fillcsr<<<nb_e, 256, 0, stream>>>(row, col, ew, ptr, rank, spair, e);
  k_degdis<<<nb_n, 256, 0, stream>>>(ptr, spair, dis, n);
  k_scale<<<nb_e, 256, 0, stream>>>(spair, dis, e);

  // layer 1: combined [x@W1 -> bf16 hwb | x@pW + pb -> f32 bufR]
  k_gemm1m<<<nb_g, 256, 0, stream>>>(x, W1, pW, pb, hwb, bufR, n);
  hipMemsetAsync(stats, 0, 128 * sizeof(float), stream);
  k_agg<<<2048, 256, 0, stream>>>(ptr, spair, dis, hwb, bufB, stats, n);
  k_bnrelu<<<nb_b, 256, 0, stream>>>(bufB, bufR, stats, g1, be1, bufA, n);

  // layer 2
  k_gemm2m<<<nb_g, 256, 0, stream>>>(bufA, W2, hwb, n);
  hipMemsetAsync(stats, 0, 128 * sizeof(float), stream);
  k_agg<<<2048, 256, 0, stream>>>(ptr, spair, dis, hwb, bufB, stats, n);
  k_bnrelu<<<nb_b, 256, 0, stream>>>(bufB, bufA, stats, g2, be2, out, n);
}

// Round 14
// 383.567 us; speedup vs baseline: 1.4443x; 1.0675x over previous
//
#include <hip/hip_runtime.h>

static constexpr float BN_EPS = 1e-5f;
typedef unsigned int uint;
typedef unsigned short ushort;
typedef __attribute__((ext_vector_type(8))) short bf16x8;
typedef __attribute__((ext_vector_type(4))) float f32x4;

__device__ __forceinline__ void fatomic_add(float* p, float v) {
  unsafeAtomicAdd(p, v);  // HW global_atomic_add_f32
}

__device__ __forceinline__ ushort f2bf(float f) {  // f32 -> bf16 RNE
  uint u = __float_as_uint(f);
  u += 0x7fffu + ((u >> 16) & 1u);
  return (ushort)(u >> 16);
}

__device__ __forceinline__ float4 bf4_decode(uint2 r) {
  return make_float4(__uint_as_float(r.x << 16), __uint_as_float(r.x & 0xffff0000u),
                     __uint_as_float(r.y << 16), __uint_as_float(r.y & 0xffff0000u));
}

// histogram keyed by col; stores each edge's arrival rank (for atomic-free fill)
__global__ void k_hist(const int* __restrict__ col, int* __restrict__ cnt,
                       int* __restrict__ rank, int e) {
  int i = blockIdx.x * 256 + threadIdx.x;
  if (i < e) rank[i] = atomicAdd(&cnt[col[i]], 1);
}

// ---- device-wide exclusive scan of cnt[n] (1024 elems/block) ----
__global__ __launch_bounds__(256) void k_scan_part(const int* __restrict__ cnt,
                                                   int* __restrict__ bsum, int n) {
  __shared__ int sm[256];
  int t = threadIdx.x;
  int base = blockIdx.x * 1024 + t * 4;
  int s = 0;
#pragma unroll
  for (int j = 0; j < 4; j++) {
    int i = base + j;
    if (i < n) s += cnt[i];
  }
  sm[t] = s;
  __syncthreads();
  for (int off = 128; off > 0; off >>= 1) {
    if (t < off) sm[t] += sm[t + off];
    __syncthreads();
  }
  if (t == 0) bsum[blockIdx.x] = sm[0];
}

__global__ __launch_bounds__(1024) void k_scan_mid(int* __restrict__ bsum, int nb) {
  __shared__ int sm[1024];
  int t = threadIdx.x;
  int v = (t < nb) ? bsum[t] : 0;
  sm[t] = v;
  __syncthreads();
  for (int off = 1; off < 1024; off <<= 1) {
    int o = (t >= off) ? sm[t - off] : 0;
    __syncthreads();
    sm[t] += o;
    __syncthreads();
  }
  if (t < nb) bsum[t] = sm[t] - v;  // exclusive block offsets
}

__global__ __launch_bounds__(256) void k_scan_apply(const int* __restrict__ cnt,
                                                    int* __restrict__ ptr,
                                                    const int* __restrict__ bsum,
                                                    int n, int e) {
  __shared__ int sm[256];
  int t = threadIdx.x;
  int base = blockIdx.x * 1024 + t * 4;
  int v[4];
  int s = 0;
#pragma unroll
  for (int j = 0; j < 4; j++) {
    int i = base + j;
    v[j] = (i < n) ? cnt[i] : 0;
    s += v[j];
  }
  sm[t] = s;
  __syncthreads();
  for (int off = 1; off < 256; off <<= 1) {
    int o = (t >= off) ? sm[t - off] : 0;
    __syncthreads();
    sm[t] += o;
    __syncthreads();
  }
  int run = bsum[blockIdx.x] + sm[t] - s;
#pragma unroll
  for (int j = 0; j < 4; j++) {
    int i = base + j;
    if (i < n) {
      ptr[i] = run;
      run += v[j];
    }
  }
  if (blockIdx.x == 0 && t == 0) ptr[n] = e;
}

// atomic-free CSR fill: slot = ptr[col] + rank
__global__ void k_fillcsr(const int* __restrict__ row, const int* __restrict__ col,
                          const float* __restrict__ ew, const int* __restrict__ ptr,
                          const int* __restrict__ rank, int2* __restrict__ spair, int e) {
  int i = blockIdx.x * 256 + threadIdx.x;
  if (i >= e) return;
  int p = ptr[col[i]] + rank[i];
  spair[p] = make_int2(row[i], __float_as_int(ew[i]));
}

// per-node: deg = 1 (self-loop) + segment-sum of ew; dis = rsqrt(deg). No atomics.
__global__ void k_degdis(const int* __restrict__ ptr, const int2* __restrict__ spair,
                         float* __restrict__ dis, int n) {
  int v = blockIdx.x * 256 + threadIdx.x;
  if (v >= n) return;
  int b = ptr[v], en = ptr[v + 1];
  float s = 1.0f;
  for (int j = b; j < en; j++) s += __int_as_float(spair[j].y);
  dis[v] = rsqrtf(s);
}

// fold dis[row] into stored edge weight (dis[col] applied in k_agg)
__global__ void k_scale(int2* __restrict__ spair, const float* __restrict__ dis, int e) {
  int i = blockIdx.x * 256 + threadIdx.x;
  if (i >= e) return;
  int2 m = spair[i];
  spair[i] = make_int2(m.x, __float_as_int(__int_as_float(m.y) * dis[m.x]));
}

// ---- aggregation v5 + fused BN stats.
// Each 16-lane group owns a CONTIGUOUS node range [v0, v0+npg): its edges form
// one contiguous spair slice, so the depth-3 chunk pipeline streams the whole
// range without per-node drain. Node boundaries handled in the compute stage
// (group-uniform while-advance). ptr/dis for the range loaded once lane-
// parallel and read via __shfl (no memory ops during the walk); self-loop rows
// prefetched 2 nodes ahead. Out-of-range edges masked (weight 0, row -> v0).
__global__ __launch_bounds__(256) void k_agg(
    const int* __restrict__ ptr, const int2* __restrict__ spair,
    const float* __restrict__ dis, const ushort* __restrict__ hwb,
    float* __restrict__ agg, float* __restrict__ stats, int n, int npg) {
  int tid = threadIdx.x;
  int lane = tid & 63;
  int li = lane & 15;
  int gbase = lane & 48;  // group base lane within wave (0,16,32,48)
  int gidx = (blockIdx.x * 256 + tid) >> 4;  // global group id
  float st_s[4] = {0.f, 0.f, 0.f, 0.f};
  float st_q[4] = {0.f, 0.f, 0.f, 0.f};

  int v0 = gidx * npg;
  if (v0 < n) {
    int v1 = min(v0 + npg, n);
    int tmax = v1 - v0;  // <= npg <= 15
    // lane-parallel ptr/dis for the range
    int pv = ptr[min(v0 + li, n)];
    float dvr = dis[min(v0 + li, n - 1)];
    int begR = __shfl(pv, gbase);
    int jend = __shfl(pv, gbase + tmax);

    // node-walk state
    int v = v0, t = 0;
    float d = __shfl(dvr, gbase);
    int e_cur = __shfl(pv, gbase + 1);
    uint2 self_cur = *(const uint2*)(hwb + (size_t)v0 * 64 + li * 4);
    uint2 self_nxt = *(const uint2*)(hwb + (size_t)min(v0 + 1, n - 1) * 64 + li * 4);
    int vself = v0 + 2;
    float4 acc = make_float4(0.f, 0.f, 0.f, 0.f);

#define FINALIZE_NODE()                                                        \
  {                                                                            \
    float4 sf = bf4_decode(self_cur);                                          \
    float4 o;                                                                  \
    o.x = d * fmaf(d, sf.x, acc.x);                                            \
    o.y = d * fmaf(d, sf.y, acc.y);                                            \
    o.z = d * fmaf(d, sf.z, acc.z);                                            \
    o.w = d * fmaf(d, sf.w, acc.w);                                            \
    *(float4*)(agg + (size_t)v * 64 + li * 4) = o;                             \
    st_s[0] += o.x; st_s[1] += o.y; st_s[2] += o.z; st_s[3] += o.w;            \
    st_q[0] = fmaf(o.x, o.x, st_q[0]);                                         \
    st_q[1] = fmaf(o.y, o.y, st_q[1]);                                         \
    st_q[2] = fmaf(o.z, o.z, st_q[2]);                                         \
    st_q[3] = fmaf(o.w, o.w, st_q[3]);                                         \
    acc = make_float4(0.f, 0.f, 0.f, 0.f);                                     \
    self_cur = self_nxt;                                                       \
    self_nxt = *(const uint2*)(hwb + (size_t)min(vself, n - 1) * 64 + li * 4); \
    vself++;                                                                   \
    v++; t++;                                                                  \
    d = __shfl(dvr, gbase + min(t, 15));                                       \
    e_cur = __shfl(pv, gbase + min(t + 1, 15));                                \
  }

    if (begR < jend) {
      const int4* sp = (const int4*)spair;
      int jc = begR & ~3;
      int h = jc >> 1;
      int nch = (jend - jc + 3) >> 2;

      float wA[4], wB[4], wC_[4];
      uint2 gA[4], gB[4], gC_[4];
      int4 mN0, mN1;

      {  // prologue chunk 0
        int4 p0 = sp[h], p1 = sp[h + 1];
        int rr[4] = {p0.x, p0.z, p1.x, p1.z};
        int wi[4] = {p0.y, p0.w, p1.y, p1.w};
#pragma unroll
        for (int k = 0; k < 4; k++) {
          int j = jc + k;
          bool okk = (j >= begR) && (j < jend);
          int r = okk ? rr[k] : v0;
          wA[k] = okk ? __int_as_float(wi[k]) : 0.f;
          gA[k] = *(const uint2*)(hwb + (size_t)r * 64 + li * 4);
        }
      }
      if (nch > 1) {  // chunk 1
        int4 p0 = sp[h + 2], p1 = sp[h + 3];
        int rr[4] = {p0.x, p0.z, p1.x, p1.z};
        int wi[4] = {p0.y, p0.w, p1.y, p1.w};
#pragma unroll
        for (int k = 0; k < 4; k++) {
          bool okk = (jc + 4 + k) < jend;
          int r = okk ? rr[k] : v0;
          wB[k] = okk ? __int_as_float(wi[k]) : 0.f;
          gB[k] = *(const uint2*)(hwb + (size_t)r * 64 + li * 4);
        }
      }
      if (nch > 2) {  // chunk 2
        int4 p0 = sp[h + 4], p1 = sp[h + 5];
        int rr[4] = {p0.x, p0.z, p1.x, p1.z};
        int wi[4] = {p0.y, p0.w, p1.y, p1.w};
#pragma unroll
        for (int k = 0; k < 4; k++) {
          bool okk = (jc + 8 + k) < jend;
          int r = okk ? rr[k] : v0;
          wC_[k] = okk ? __int_as_float(wi[k]) : 0.f;
          gC_[k] = *(const uint2*)(hwb + (size_t)r * 64 + li * 4);
        }
      }
      if (nch > 3) { mN0 = sp[h + 6]; mN1 = sp[h + 7]; }

      for (int c = 0; c < nch; c++) {
        float wD[4];
        uint2 gD[4];
        if (c + 3 < nch) {  // issue gathers for chunk c+3
          int jn = jc + 12;
          int rr[4] = {mN0.x, mN0.z, mN1.x, mN1.z};
          int wi[4] = {mN0.y, mN0.w, mN1.y, mN1.w};
#pragma unroll
          for (int k = 0; k < 4; k++) {
            bool okk = (jn + k) < jend;
            int r = okk ? rr[k] : v0;
            wD[k] = okk ? __int_as_float(wi[k]) : 0.f;
            gD[k] = *(const uint2*)(hwb + (size_t)r * 64 + li * 4);
          }
        }
        if (c + 4 < nch) {  // prefetch meta for chunk c+4
          mN0 = sp[h + 2 * (c + 4)];
          mN1 = sp[h + 2 * (c + 4) + 1];
        }
        // compute chunk c with node-boundary advance
#pragma unroll
        for (int k = 0; k < 4; k++) {
          int j = jc + k;
          while (j >= e_cur && v < v1) FINALIZE_NODE();
          float4 f = bf4_decode(gA[k]);
          acc.x = fmaf(wA[k], f.x, acc.x);
          acc.y = fmaf(wA[k], f.y, acc.y);
          acc.z = fmaf(wA[k], f.z, acc.z);
          acc.w = fmaf(wA[k], f.w, acc.w);
        }
#pragma unroll
        for (int k = 0; k < 4; k++) {
          gA[k] = gB[k]; wA[k] = wB[k];
          gB[k] = gC_[k]; wB[k] = wC_[k];
        }
        if (c + 3 < nch) {
#pragma unroll
          for (int k = 0; k < 4; k++) { gC_[k] = gD[k]; wC_[k] = wD[k]; }
        }
        jc += 4;
      }
    }
    // epilogue: finalize remaining nodes (incl. zero-degree / tail)
    while (v < v1) FINALIZE_NODE();
#undef FINALIZE_NODE
  }

  // cross-group + block stats reduction
#pragma unroll
  for (int j = 0; j < 4; j++) {
    st_s[j] += __shfl_xor(st_s[j], 16);
    st_s[j] += __shfl_xor(st_s[j], 32);
    st_q[j] += __shfl_xor(st_q[j], 16);
    st_q[j] += __shfl_xor(st_q[j], 32);
  }
  __shared__ float rs[4][64];
  __shared__ float rq[4][64];
  int wv = tid >> 6;
  if (gbase == 0) {
#pragma unroll
    for (int j = 0; j < 4; j++) {
      rs[wv][li * 4 + j] = st_s[j];
      rq[wv][li * 4 + j] = st_q[j];
    }
  }
  __syncthreads();
  if (tid < 64) {
    int c = tid;
    float s = rs[0][c] + rs[1][c] + rs[2][c] + rs[3][c];
    float q = rq[0][c] + rq[1][c] + rq[2][c] + rq[3][c];
    fatomic_add(&stats[c], s);
    fatomic_add(&stats[64 + c], q);
  }
}

// ---- GEMM1 via MFMA: [n,128] @ [128,128]. (unchanged from R12)
__global__ __launch_bounds__(256) void k_gemm1m(
    const float* __restrict__ x, const float* __restrict__ W1,
    const float* __restrict__ pW, const float* __restrict__ pb,
    ushort* __restrict__ ob, float* __restrict__ of, int n) {
  __shared__ ushort wT[128 * 128];  // 32 KB
  int tid = threadIdx.x;
  for (int idx = tid; idx < 128 * 64; idx += 256) {
    int c = idx >> 6;
    int kp = idx & 63;
    const float* src = (c < 64) ? (W1 + c) : (pW + (c - 64));
    float f0 = src[(size_t)(2 * kp) * 64];
    float f1 = src[(size_t)(2 * kp + 1) * 64];
    uint pk = (uint)f2bf(f0) | ((uint)f2bf(f1) << 16);
    int byte = c * 256 + kp * 4;
    byte ^= ((c & 7) << 4);
    *(uint*)((char*)wT + byte) = pk;
  }
  __syncthreads();

  int lane = tid & 63;
  int wv = tid >> 6;
  int lr = lane & 15;
  int lk = lane >> 4;
  int rowBase = blockIdx.x * 128 + wv * 32;

  f32x4 acc[2][8];
#pragma unroll
  for (int i = 0; i < 2; i++)
#pragma unroll
    for (int j = 0; j < 8; j++) acc[i][j] = (f32x4){0.f, 0.f, 0.f, 0.f};

  int r0 = rowBase + lr;
  int r1 = rowBase + 16 + lr;
  bool ok0 = r0 < n, ok1 = r1 < n;
  int swz = (lr & 7) << 4;

#pragma unroll
  for (int ks = 0; ks < 4; ks++) {
    int k0 = ks * 32 + lk * 8;
    bf16x8 a0 = (bf16x8)(short)0, a1 = (bf16x8)(short)0;
    if (ok0) {
      const float4* xp = (const float4*)(x + (size_t)r0 * 128 + k0);
      float4 v0 = xp[0], v1 = xp[1];
      a0[0] = (short)f2bf(v0.x); a0[1] = (short)f2bf(v0.y);
      a0[2] = (short)f2bf(v0.z); a0[3] = (short)f2bf(v0.w);
      a0[4] = (short)f2bf(v1.x); a0[5] = (short)f2bf(v1.y);
      a0[6] = (short)f2bf(v1.z); a0[7] = (short)f2bf(v1.w);
    }
    if (ok1) {
      const float4* xp = (const float4*)(x + (size_t)r1 * 128 + k0);
      float4 v0 = xp[0], v1 = xp[1];
      a1[0] = (short)f2bf(v0.x); a1[1] = (short)f2bf(v0.y);
      a1[2] = (short)f2bf(v0.z); a1[3] = (short)f2bf(v0.w);
      a1[4] = (short)f2bf(v1.x); a1[5] = (short)f2bf(v1.y);
      a1[6] = (short)f2bf(v1.z); a1[7] = (short)f2bf(v1.w);
    }
#pragma unroll
    for (int ct = 0; ct < 8; ct++) {
      int byte = ((ct * 16 + lr) * 128 + k0) * 2;
      byte ^= swz;
      bf16x8 b = *(const bf16x8*)((const char*)wT + byte);
      acc[0][ct] = __builtin_amdgcn_mfma_f32_16x16x32_bf16(a0, b, acc[0][ct], 0, 0, 0);
      acc[1][ct] = __builtin_amdgcn_mfma_f32_16x16x32_bf16(a1, b, acc[1][ct], 0, 0, 0);
    }
  }

  float bias[4];
#pragma unroll
  for (int q = 0; q < 4; q++) bias[q] = pb[q * 16 + lr];

#pragma unroll
  for (int rt = 0; rt < 2; rt++) {
#pragma unroll
    for (int e = 0; e < 4; e++) {
      int r = rowBase + rt * 16 + lk * 4 + e;
      if (r >= n) continue;
#pragma unroll
      for (int ct = 0; ct < 4; ct++)
        ob[(size_t)r * 64 + ct * 16 + lr] = f2bf(acc[rt][ct][e]);
#pragma unroll
      for (int ct = 4; ct < 8; ct++)
        of[(size_t)r * 64 + (ct - 4) * 16 + lr] = acc[rt][ct][e] + bias[ct - 4];
    }
  }
}

// ---- GEMM2 via MFMA: [n,64] @ [64,64] -> bf16 hwb. (unchanged from R12)
__global__ __launch_bounds__(256) void k_gemm2m(
    const float* __restrict__ h, const float* __restrict__ W2,
    ushort* __restrict__ ob, int n) {
  __shared__ ushort wT[64 * 64];  // 8 KB
  int tid = threadIdx.x;
  for (int idx = tid; idx < 64 * 32; idx += 256) {
    int c = idx >> 5;
    int kp = idx & 31;
    float f0 = W2[(size_t)(2 * kp) * 64 + c];
    float f1 = W2[(size_t)(2 * kp + 1) * 64 + c];
    uint pk = (uint)f2bf(f0) | ((uint)f2bf(f1) << 16);
    int byte = c * 128 + kp * 4;
    byte ^= ((c & 7) << 4);
    *(uint*)((char*)wT + byte) = pk;
  }
  __syncthreads();

  int lane = tid & 63;
  int wv = tid >> 6;
  int lr = lane & 15;
  int lk = lane >> 4;
  int rowBase = blockIdx.x * 128 + wv * 32;

  f32x4 acc[2][4];
#pragma unroll
  for (int i = 0; i < 2; i++)
#pragma unroll
    for (int j = 0; j < 4; j++) acc[i][j] = (f32x4){0.f, 0.f, 0.f, 0.f};

  int r0 = rowBase + lr;
  int r1 = rowBase + 16 + lr;
  bool ok0 = r0 < n, ok1 = r1 < n;
  int swz = (lr & 7) << 4;

#pragma unroll
  for (int ks = 0; ks < 2; ks++) {
    int k0 = ks * 32 + lk * 8;
    bf16x8 a0 = (bf16x8)(short)0, a1 = (bf16x8)(short)0;
    if (ok0) {
      const float4* xp = (const float4*)(h + (size_t)r0 * 64 + k0);
      float4 v0 = xp[0], v1 = xp[1];
      a0[0] = (short)f2bf(v0.x); a0[1] = (short)f2bf(v0.y);
      a0[2] = (short)f2bf(v0.z); a0[3] = (short)f2bf(v0.w);
      a0[4] = (short)f2bf(v1.x); a0[5] = (short)f2bf(v1.y);
      a0[6] = (short)f2bf(v1.z); a0[7] = (short)f2bf(v1.w);
    }
    if (ok1) {
      const float4* xp = (const float4*)(h + (size_t)r1 * 64 + k0);
      float4 v0 = xp[0], v1 = xp[1];
      a1[0] = (short)f2bf(v0.x); a1[1] = (short)f2bf(v0.y);
      a1[2] = (short)f2bf(v0.z); a1[3] = (short)f2bf(v0.w);
      a1[4] = (short)f2bf(v1.x); a1[5] = (short)f2bf(v1.y);
      a1[6] = (short)f2bf(v1.z); a1[7] = (short)f2bf(v1.w);
    }
#pragma unroll
    for (int ct = 0; ct < 4; ct++) {
      int byte = ((ct * 16 + lr) * 64 + k0) * 2;
      byte ^= swz;
      bf16x8 b = *(const bf16x8*)((const char*)wT + byte);
      acc[0][ct] = __builtin_amdgcn_mfma_f32_16x16x32_bf16(a0, b, acc[0][ct], 0, 0, 0);
      acc[1][ct] = __builtin_amdgcn_mfma_f32_16x16x32_bf16(a1, b, acc[1][ct], 0, 0, 0);
    }
  }

#pragma unroll
  for (int rt = 0; rt < 2; rt++) {
#pragma unroll
    for (int e = 0; e < 4; e++) {
      int r = rowBase + rt * 16 + lk * 4 + e;
      if (r >= n) continue;
#pragma unroll
      for (int ct = 0; ct < 4; ct++)
        ob[(size_t)r * 64 + ct * 16 + lr] = f2bf(acc[rt][ct][e]);
    }
  }
}

// out = relu(g*(agg-mu)*rsqrt(var+eps)+beta) + res   (conv bias cancels in BN)
__global__ __launch_bounds__(256) void k_bnrelu(
    const float* __restrict__ agg, const float* __restrict__ res,
    const float* __restrict__ stats, const float* __restrict__ g,
    const float* __restrict__ beta, float* __restrict__ out, int n) {
  int idx = blockIdx.x * 256 + threadIdx.x;
  if (idx >= n * 16) return;
  int c4 = (idx & 15) * 4;
  float invN = 1.0f / (float)n;
  float4 a = ((const float4*)agg)[idx];
  float4 rr = ((const float4*)res)[idx];
  float av[4] = {a.x, a.y, a.z, a.w};
  float rv[4] = {rr.x, rr.y, rr.z, rr.w};
  float vo[4];
#pragma unroll
  for (int j = 0; j < 4; j++) {
    int c = c4 + j;
    float mu = stats[c] * invN;
    float var = stats[64 + c] * invN - mu * mu;
    float sc = g[c] * rsqrtf(var + BN_EPS);
    float v = (av[j] - mu) * sc + beta[c];
    vo[j] = fmaxf(v, 0.0f) + rv[j];
  }
  ((float4*)out)[idx] = make_float4(vo[0], vo[1], vo[2], vo[3]);
}

extern "C" void kernel_launch(void* const* d_in, const int* in_sizes, int n_in,
                              void* d_out, int out_size, void* d_ws, size_t ws_size,
                              hipStream_t stream) {
  const float* x = (const float*)d_in[0];
  const int* ei = (const int*)d_in[1];
  const float* ew = (const float*)d_in[2];
  const float* W1 = (const float*)d_in[3];
  const float* g1 = (const float*)d_in[5];
  const float* be1 = (const float*)d_in[6];
  const float* W2 = (const float*)d_in[7];
  const float* g2 = (const float*)d_in[9];
  const float* be2 = (const float*)d_in[10];
  const float* pW = (const float*)d_in[11];
  const float* pb = (const float*)d_in[12];

  int n = in_sizes[0] / 128;
  int e = in_sizes[1] / 2;
  const int* row = ei;      // source
  const int* col = ei + e;  // target

  // workspace layout (spair padded by 32 int2: streaming k_agg may over-READ
  // meta past a group's range; masked before use)
  float* ws = (float*)d_ws;
  float* dis = ws;                             // n
  int* ptr = (int*)(dis + n);                  // n+4
  int* cnt = ptr + n + 4;                      // n
  int* rank = cnt + n;                         // e
  int* bsum = rank + e;                        // 1024
  int2* spair = (int2*)(bsum + 1024);          // e int2 (+32 pad)
  ushort* hwb = (ushort*)(spair + e + 32);     // n*64 bf16 (hw1, then hw2)
  float* bufR = (float*)(hwb + (size_t)n * 64);  // n*64 (residual)
  float* bufB = bufR + (size_t)n * 64;         // n*64 (agg)
  float* bufA = bufB + (size_t)n * 64;         // n*64 (h)
  float* stats = bufA + (size_t)n * 64;        // 128

  float* out = (float*)d_out;

  int nb_n = (n + 255) / 256;
  int nb_e = (e + 255) / 256;
  int nb_b = (n * 16 + 255) / 256;
  int nb_sc = (n + 1023) / 1024;
  int nb_g = (n + 127) / 128;

  // k_agg geometry: 1024 blocks x 16 groups = 16384 contiguous node ranges
  constexpr int AGG_BLOCKS = 1024;
  int ngroups = AGG_BLOCKS * 16;
  int npg = (n + ngroups - 1) / ngroups;  // nodes per group (<= 15 for n <= 245760)

  // CSR build + gcn_norm
  hipMemsetAsync(cnt, 0, n * sizeof(int), stream);
  k_hist<<<nb_e, 256, 0, stream>>>(col, cnt, rank, e);
  k_scan_part<<<nb_sc, 256, 0, stream>>>(cnt, bsum, n);
  k_scan_mid<<<1, 1024, 0, stream>>>(bsum, nb_sc);
  k_scan_apply<<<nb_sc, 256, 0, stream>>>(cnt, ptr, bsum, n, e);
  k_fillcsr<<<nb_e, 256, 0, stream>>>(row, col, ew, ptr, rank, spair, e);
  k_degdis<<<nb_n, 256, 0, stream>>>(ptr, spair, dis, n);
  k_scale<<<nb_e, 256, 0, stream>>>(spair, dis, e);

  // layer 1: combined [x@W1 -> bf16 hwb | x@pW + pb -> f32 bufR]
  k_gemm1m<<<nb_g, 256, 0, stream>>>(x, W1, pW, pb, hwb, bufR, n);
  hipMemsetAsync(stats, 0, 128 * sizeof(float), stream);
  k_agg<<<AGG_BLOCKS, 256, 0, stream>>>(ptr, spair, dis, hwb, bufB, stats, n, npg);
  k_bnrelu<<<nb_b, 256, 0, stream>>>(bufB, bufR, stats, g1, be1, bufA, n);

  // layer 2
  k_gemm2m<<<nb_g, 256, 0, stream>>>(bufA, W2, hwb, n);
  hipMemsetAsync(stats, 0, 128 * sizeof(float), stream);
  k_agg<<<AGG_BLOCKS, 256, 0, stream>>>(ptr, spair, dis, hwb, bufB, stats, n, npg);
  k_bnrelu<<<nb_b, 256, 0, stream>>>(bufB, bufA, stats, g2, be2, out, n);
}